// Round 6
// baseline (579.153 us; speedup 1.0000x reference)
//
#include <hip/hip_runtime.h>
#include <hip/hip_bf16.h>
#include <cstdint>

#define DI __device__ __forceinline__

typedef __attribute__((ext_vector_type(4))) float f32x4;
typedef __attribute__((ext_vector_type(16))) float f32x16;
typedef __attribute__((ext_vector_type(8))) short s16x8;
typedef __attribute__((ext_vector_type(4))) short s16x4;
typedef __attribute__((ext_vector_type(4))) unsigned int u32x4;
typedef unsigned int u32;

constexpr int Sc = 2048;
constexpr float LOG2E = 1.44269504088896340736f;
// B=4, D=1024, H=16, DK=64, M = B*S = 8192, BH = 64

DI short f2bf(float x) {
    __hip_bfloat16 h = __float2bfloat16(x);
    return __builtin_bit_cast(short, h);
}
DI float bf2f(short x) {
    __hip_bfloat16 h = __builtin_bit_cast(__hip_bfloat16, x);
    return __bfloat162float(h);
}
// pack two f32 -> dword of 2 bf16 (lo = a, hi = b) via verified scalar converts
DI u32 pack2(float a, float b) {
    return (u32)(unsigned short)f2bf(a) | ((u32)(unsigned short)f2bf(b) << 16);
}

// async 16B global -> LDS (dest = wave-uniform base + lane*16)
DI void cp16(const short* g, short* l) {
    __builtin_amdgcn_global_load_lds(
        (const __attribute__((address_space(1))) u32*)g,
        (__attribute__((address_space(3))) u32*)l, 16, 0, 0);
}

DI float fexp2(float x) {
#if __has_builtin(__builtin_amdgcn_exp2f)
    return __builtin_amdgcn_exp2f(x);
#else
    return exp2f(x);
#endif
}
DI float frcp(float x) {
#if __has_builtin(__builtin_amdgcn_rcpf)
    return __builtin_amdgcn_rcpf(x);
#else
    return 1.0f / x;
#endif
}

// ---- X [8192][1024] f32 -> X2 [8192][2048] bf16 : cols [0,1024)=hi, [1024,2048)=lo
__global__ void xconv_kernel(const float* __restrict__ X, short* __restrict__ X2) {
    size_t i = ((size_t)blockIdx.x * 256 + threadIdx.x) * 4;
    float4 v = *reinterpret_cast<const float4*>(X + i);
    int m = (int)(i >> 10);
    int k = (int)(i & 1023);
    float vv[4] = {v.x, v.y, v.z, v.w};
    short hi[4], lo[4];
#pragma unroll
    for (int j = 0; j < 4; ++j) { hi[j] = f2bf(vv[j]); lo[j] = f2bf(vv[j] - bf2f(hi[j])); }
    s16x4 h4 = {hi[0], hi[1], hi[2], hi[3]};
    s16x4 l4 = {lo[0], lo[1], lo[2], lo[3]};
    *reinterpret_cast<s16x4*>(X2 + (size_t)m * 2048 + k) = h4;
    *reinterpret_cast<s16x4*>(X2 + (size_t)m * 2048 + 1024 + k) = l4;
}

// ---- Wq/Wk/Wv [1024][1024] f32 -> WT2 [3072][2048] bf16 (transposed; [n][k]: hi at k, lo at 1024+k)
__global__ void wqkv_conv(const float* __restrict__ Wq, const float* __restrict__ Wk,
                          const float* __restrict__ Wv, short* __restrict__ WT2) {
    __shared__ float t[32][33];
    int z = blockIdx.z;
    const float* W = (z == 0) ? Wq : (z == 1 ? Wk : Wv);
    int k0 = blockIdx.x * 32, n0 = blockIdx.y * 32;
    int tx = threadIdx.x, ty = threadIdx.y;
#pragma unroll
    for (int i = 0; i < 4; ++i)
        t[ty + 8 * i][tx] = W[(size_t)(k0 + ty + 8 * i) * 1024 + n0 + tx];
    __syncthreads();
#pragma unroll
    for (int i = 0; i < 4; ++i) {
        float v = t[tx][ty + 8 * i];
        short hi = f2bf(v), lo = f2bf(v - bf2f(hi));
        size_t r = (size_t)(z * 1024 + n0 + ty + 8 * i) * 2048 + k0 + tx;
        WT2[r] = hi;
        WT2[r + 1024] = lo;
    }
}

// ---- Wo [1024][1024] f32 -> WoT [1024][1024] bf16 (transposed, hi only)
__global__ void wo_conv(const float* __restrict__ Wo, short* __restrict__ WoT) {
    __shared__ float t[32][33];
    int k0 = blockIdx.x * 32, n0 = blockIdx.y * 32;
    int tx = threadIdx.x, ty = threadIdx.y;
#pragma unroll
    for (int i = 0; i < 4; ++i)
        t[ty + 8 * i][tx] = Wo[(size_t)(k0 + ty + 8 * i) * 1024 + n0 + tx];
    __syncthreads();
#pragma unroll
    for (int i = 0; i < 4; ++i)
        WoT[(size_t)(n0 + ty + 8 * i) * 1024 + k0 + tx] = f2bf(t[tx][ty + 8 * i]);
}

// ---- bias table [16][4096] bf16, PRE-SCALED by log2(e): tab[h][delta+2047] = log2e*rel_bias[bucket][h]
// Exact integer thresholds equivalent to int(log(rel/8)/log(16)*8) under correctly-rounded log.
__global__ void bias_kernel(const float* __restrict__ rel_bias, short* __restrict__ tab) {
    int idx = blockIdx.x * 256 + threadIdx.x;  // 16*4096
    int h = idx >> 12;
    int i = idx & 4095;
    int delta = i - 2047;
    int ad = delta < 0 ? -delta : delta;
    int b;
    if (ad < 8) b = ad;
    else if (ad < 12) b = 8;
    else if (ad < 16) b = 9;
    else if (ad < 23) b = 10;
    else if (ad < 32) b = 11;
    else if (ad < 46) b = 12;
    else if (ad < 64) b = 13;
    else if (ad < 91) b = 14;
    else b = 15;
    if (delta > 0) b += 16;
    tab[idx] = f2bf(rel_bias[b * 16 + h] * LOG2E);
}

// ---- GEMM, pipelined: 256x256 tile, BK=32, 8 waves (2M x 4N, per-wave 128x64).
// Triple-buffered LDS (96KB), stage tile t+2 during tile t via global_load_lds with
// pre-swizzled global source (T2; linear LDS dest), counted s_waitcnt vmcnt(4) at tile
// boundaries (T4 -- never 0 mid-loop), 2 phases x 16 MFMA per tile with setprio (T3/T5).
// Correctness: per-thread VMEM FIFO -> at boundary entering tile t+1 the outstanding
// loads are exactly t+2's 4 (+maybe t+1's); vmcnt(4) retires everything older, so t+1's
// tile is LDS-resident after the barrier. Buf(t+2)%3 went dead at the previous barrier.
// Split-K' remap via aWrap/bWrap. EPI=0: fp32 C. EPI=1: Q'(log2e, hi|lo), K'(hi|lo), V^T.
template <int EPI>
__launch_bounds__(512, 1)
__global__ void gemm2(const short* __restrict__ A, const short* __restrict__ Bt,
                      int K, int lda, int ldb, int aWrap, int bWrap,
                      float* __restrict__ C, int ldc,
                      short* __restrict__ q2, short* __restrict__ k2, short* __restrict__ vt) {
    __shared__ __align__(16) short As[3][256 * 32];
    __shared__ __align__(16) short Bs[3][256 * 32];
    const int tid = threadIdx.x;
    const int w = tid >> 6, l = tid & 63;
    const int wm = w >> 2, wn = w & 3;
    const int rl = l >> 4, cl = l & 15;

    // XCD-aware swizzle (grid % 8 == 0 for both launches)
    const int cpx = gridDim.x >> 3;
    const int swz = ((int)blockIdx.x & 7) * cpx + ((int)blockIdx.x >> 3);
    const int m0 = (swz & 31) * 256;
    const int n0 = (swz >> 5) * 256;

    f32x4 acc[8][4];
#pragma unroll
    for (int i = 0; i < 8; ++i)
#pragma unroll
        for (int j = 0; j < 4; ++j) acc[i][j] = (f32x4){0.f, 0.f, 0.f, 0.f};

    const int NT = K / 32;
    // staging: per-tile 2 A-loads + 2 B-loads per thread; swizzle slot = c ^ ((r>>1)&3)
    const int sr = tid >> 2;                       // row within 128-row group
    const int scg = (tid & 3) ^ ((tid >> 3) & 3);  // swizzled chunk (constant per thread)
    auto stageA = [&](int buf, int t, int j) {
        int kk = t * 32;
        int ca = kk - (kk >= aWrap ? aWrap : 0);
        cp16(A + (size_t)(m0 + j * 128 + sr) * lda + ca + scg * 8,
             &As[buf][(j * 512 + w * 64) * 8]);
    };
    auto stageB = [&](int buf, int t, int j) {
        int kk = t * 32;
        int cb = kk - (kk >= bWrap ? bWrap : 0);
        cp16(Bt + (size_t)(n0 + j * 128 + sr) * ldb + cb + scg * 8,
             &Bs[buf][(j * 512 + w * 64) * 8]);
    };

    // fragment-read addressing (swizzle is static per lane: (row0+16i)>>1 keeps &3)
    const int rowA0 = wm * 128 + cl;
    const int rowB0 = wn * 64 + cl;
    const int slA = (rl ^ ((rowA0 >> 1) & 3)) * 8;
    const int slB = (rl ^ ((rowB0 >> 1) & 3)) * 8;

    // prologue: stage tiles 0 and 1
    stageA(0, 0, 0); stageA(0, 0, 1); stageB(0, 0, 0); stageB(0, 0, 1);
    stageA(1, 1, 0); stageA(1, 1, 1); stageB(1, 1, 0); stageB(1, 1, 1);
    asm volatile("s_waitcnt vmcnt(4)" ::: "memory");
    __builtin_amdgcn_s_barrier();

    for (int t = 0; t < NT; ++t) {
        const int buf = t % 3;
        const int sbuf = (t + 2) % 3;
        const bool dost = (t + 2) < NT;
        const short* Ab = &As[buf][rowA0 * 32 + slA];
        const short* Bb = &Bs[buf][rowB0 * 32 + slB];

        // B frags (shared by both phases)
        s16x8 bfv[4];
#pragma unroll
        for (int ni = 0; ni < 4; ++ni)
            bfv[ni] = *reinterpret_cast<const s16x8*>(Bb + ni * 512);

        // phase 0 (rows 0..63 of wave tile)
        if (dost) { stageA(sbuf, t + 2, 0); stageB(sbuf, t + 2, 0); }
        {
            s16x8 af[4];
#pragma unroll
            for (int i = 0; i < 4; ++i)
                af[i] = *reinterpret_cast<const s16x8*>(Ab + i * 512);
            __builtin_amdgcn_s_setprio(1);
#pragma unroll
            for (int i = 0; i < 4; ++i)
#pragma unroll
                for (int ni = 0; ni < 4; ++ni)
                    acc[i][ni] = __builtin_amdgcn_mfma_f32_16x16x32_bf16(af[i], bfv[ni], acc[i][ni], 0, 0, 0);
            __builtin_amdgcn_s_setprio(0);
        }
        __builtin_amdgcn_s_barrier();

        // phase 1 (rows 64..127)
        if (dost) { stageA(sbuf, t + 2, 1); stageB(sbuf, t + 2, 1); }
        {
            s16x8 af[4];
#pragma unroll
            for (int i = 0; i < 4; ++i)
                af[i] = *reinterpret_cast<const s16x8*>(Ab + (4 + i) * 512);
            __builtin_amdgcn_s_setprio(1);
#pragma unroll
            for (int i = 0; i < 4; ++i)
#pragma unroll
                for (int ni = 0; ni < 4; ++ni)
                    acc[4 + i][ni] = __builtin_amdgcn_mfma_f32_16x16x32_bf16(af[i], bfv[ni], acc[4 + i][ni], 0, 0, 0);
            __builtin_amdgcn_s_setprio(0);
        }

        if (t + 1 < NT) {
            if (dost) asm volatile("s_waitcnt vmcnt(4)" ::: "memory");
            else      asm volatile("s_waitcnt vmcnt(0)" ::: "memory");
            __builtin_amdgcn_s_barrier();
        }
    }

    if (EPI == 0) {
#pragma unroll
        for (int mi = 0; mi < 8; ++mi) {
            int row = m0 + wm * 128 + mi * 16 + rl * 4;
#pragma unroll
            for (int ni = 0; ni < 4; ++ni) {
                int col = n0 + wn * 64 + ni * 16 + cl;
#pragma unroll
                for (int r = 0; r < 4; ++r)
                    C[(size_t)(row + r) * ldc + col] = acc[mi][ni][r];
            }
        }
    } else {
        int region = n0 >> 10;  // block-uniform: 0=Q 1=K 2=V
#pragma unroll
        for (int mi = 0; mi < 8; ++mi) {
#pragma unroll
            for (int ni = 0; ni < 4; ++ni) {
#pragma unroll
                for (int r = 0; r < 4; ++r) {
                    int m = m0 + wm * 128 + mi * 16 + rl * 4 + r;
                    int n = (n0 & 1023) + wn * 64 + ni * 16 + cl;
                    int bb = m >> 11, s = m & 2047;
                    int h = n >> 6, d = n & 63;
                    int bh = bb * 16 + h;
                    float c = acc[mi][ni][r];
                    if (region == 0) {
                        c *= LOG2E;  // fold softmax base-2 conversion into Q
                        short hi = f2bf(c);
                        short lo = f2bf(c - bf2f(hi));
                        size_t base = ((size_t)bh * 2048 + s) * 128;
                        q2[base + d] = hi;
                        q2[base + 64 + d] = lo;
                    } else if (region == 1) {
                        short hi = f2bf(c);
                        short lo = f2bf(c - bf2f(hi));
                        size_t base = ((size_t)bh * 2048 + s) * 128;
                        k2[base + d] = hi;
                        k2[base + 64 + d] = lo;
                    } else {
                        vt[((size_t)bh * 64 + d) * 2048 + s] = f2bf(c);
                    }
                }
            }
        }
    }
}

// ---- Flash attention, 32x32 swapped-operand form (validated r5).
// Grid: 512 blocks (XCD-swizzled), 512 threads = 8 waves; wave owns 32 q-rows (q-block 256).
// Swapped QK: mfma(A=K', B=Q') -> lane holds 16 scores of ONE q-row (q = lane&31).
// P stays in registers; cross-half exchange via verified __shfl_xor(32) + select.
// No online max (|score*log2e| < ~90 << 127, exp2/fp32-sum safe); psum is in-lane scalar.
__launch_bounds__(512, 4)
__global__ void flash_kernel(const short* __restrict__ q2, const short* __restrict__ k2,
                             const short* __restrict__ vt, const short* __restrict__ btab,
                             short* __restrict__ attnb) {
    __shared__ __align__(16) short Ks[2][8192];   // [buf] 64 rows x 16 chunks(16B), slot = c ^ (r&15)
    __shared__ __align__(16) short Vs[2][4096];   // [buf] 64 d-rows x 8 chunks, slot = c ^ (d&7)
    __shared__ __align__(16) short Bsh[2304];     // bias slice (bf16, log2e-scaled)

    const int tid = threadIdx.x;
    const int w = tid >> 6, l = tid & 63;
    const int l31 = l & 31, hi = l >> 5;

    const int L = blockIdx.x;
    const int xcd = L & 7, idx = L >> 3;
    const int bh = xcd + 8 * (idx & 7);
    const int qb = idx >> 3;
    const int h = bh & 15;
    const int q0b = qb * 256;
    const int qw0 = q0b + w * 32;
    const int qL = w * 32 + l31;

    const short* Q = q2 + (size_t)bh * Sc * 128;
    const short* Kp = k2 + (size_t)bh * Sc * 128;
    const short* V = vt + (size_t)bh * 64 * Sc;

    {
        int base = h * 4096 + 1792 - q0b;
        for (int i = tid; i < 2304; i += 512) Bsh[i] = btab[base + i];
    }

    auto stage = [&](int buf, int it2) {
        int kv0 = it2 * 64;
#pragma unroll
        for (int j = 0; j < 2; ++j) {
            int o = w * 128 + j * 64 + l;
            int r = o >> 4, cs = o & 15;
            int cg = cs ^ (r & 15);
            cp16(Kp + (size_t)(kv0 + r) * 128 + cg * 8, &Ks[buf][(w * 128 + j * 64) * 8]);
        }
        {
            int o = w * 64 + l;
            int d = o >> 3, cs = o & 7;
            int cg = cs ^ (d & 7);
            cp16(V + (size_t)d * 2048 + kv0 + cg * 8, &Vs[buf][(w * 64) * 8]);
        }
    };

    s16x8 qf[8];
#pragma unroll
    for (int c = 0; c < 8; ++c)
        qf[c] = *reinterpret_cast<const s16x8*>(Q + (size_t)(qw0 + l31) * 128 + c * 16 + hi * 8);

    f32x16 accO[2];
#pragma unroll
    for (int i = 0; i < 16; ++i) { accO[0][i] = 0.f; accO[1][i] = 0.f; }
    float psum = 0.f;

    stage(0, 0);
    __syncthreads();

    for (int it = 0; it < 32; ++it) {
        const int cur = it & 1;
        if (it + 1 < 32) stage(cur ^ 1, it + 1);
        const int kv0 = it * 64;
#pragma unroll
        for (int T = 0; T < 2; ++T) {
            const int rA = T * 32 + l31;
            const int rsw = rA & 15;
            const short* kbase = &Ks[cur][rA * 128];
            s16x8 kh[4];
#pragma unroll
            for (int c = 0; c < 4; ++c)
                kh[c] = *reinterpret_cast<const s16x8*>(kbase + ((c * 2 + hi) ^ rsw) * 8);
            f32x16 acc = {0.f,0.f,0.f,0.f,0.f,0.f,0.f,0.f,0.f,0.f,0.f,0.f,0.f,0.f,0.f,0.f};
#pragma unroll
            for (int c = 0; c < 4; ++c)
                acc = __builtin_amdgcn_mfma_f32_32x32x16_bf16(kh[c], qf[c], acc, 0, 0, 0);
#pragma unroll
            for (int c = 0; c < 4; ++c)
                acc = __builtin_amdgcn_mfma_f32_32x32x16_bf16(kh[c], qf[c + 4], acc, 0, 0, 0);
#pragma unroll
            for (int c = 0; c < 4; ++c) {
                s16x8 klo = *reinterpret_cast<const s16x8*>(kbase + (((c + 4) * 2 + hi) ^ rsw) * 8);
                acc = __builtin_amdgcn_mfma_f32_32x32x16_bf16(klo, qf[c], acc, 0, 0, 0);
            }
#pragma unroll
            for (int t2 = 0; t2 < 2; ++t2) {
                u32 pk[4];
#pragma unroll
                for (int i = 0; i < 4; ++i) {
                    const int ii = t2 * 4 + i;
                    const int pstart = ((ii & 1) * 2) + ((ii >> 1) * 8);
                    const int kvg = kv0 + T * 32 + pstart + 4 * hi;
                    const int i0 = kvg - qL + 255;
                    const float b0 = bf2f(Bsh[i0]);
                    const float b1 = bf2f(Bsh[i0 + 1]);
                    const int r0 = t2 * 8 + i * 2;
                    const float e0 = fexp2(acc[r0] + b0);
                    const float e1 = fexp2(acc[r0 + 1] + b1);
                    psum += e0 + e1;
                    pk[i] = pack2(e0, e1);
                }
                const u32 ex0 = __shfl_xor(pk[0], 32);
                const u32 ex1 = __shfl_xor(pk[1], 32);
                const u32 ex2 = __shfl_xor(pk[2], 32);
                const u32 ex3 = __shfl_xor(pk[3], 32);
                const u32 d0 = hi ? ex2 : pk[0];
                const u32 d1 = hi ? ex3 : pk[1];
                const u32 d2 = hi ? pk[2] : ex0;
                const u32 d3 = hi ? pk[3] : ex1;
                u32x4 pv4 = {d0, d1, d2, d3};
                s16x8 pfrag = __builtin_bit_cast(s16x8, pv4);
                const int tg = T * 2 + t2;
#pragma unroll
                for (int dt = 0; dt < 2; ++dt) {
                    const int d = dt * 32 + l31;
                    s16x8 vf = *reinterpret_cast<const s16x8*>(
                        &Vs[cur][d * 64 + ((tg * 2 + hi) ^ (d & 7)) * 8]);
                    accO[dt] = __builtin_amdgcn_mfma_f32_32x32x16_bf16(pfrag, vf, accO[dt], 0, 0, 0);
                }
            }
        }
        __syncthreads();
    }

    psum += __shfl_xor(psum, 32);

    const int bb = bh >> 4;
#pragma unroll
    for (int r = 0; r < 16; ++r) {
        const int qloc = (r & 3) + 8 * (r >> 2) + 4 * hi;
        const float inv = frcp(__shfl(psum, qloc));
        const size_t rowbase = ((size_t)(bb * 2048 + qw0 + qloc)) * 1024 + h * 64;
#pragma unroll
        for (int dt = 0; dt < 2; ++dt)
            attnb[rowbase + dt * 32 + l31] = f2bf(accO[dt][r] * inv);
    }
}

extern "C" void kernel_launch(void* const* d_in, const int* in_sizes, int n_in,
                              void* d_out, int out_size, void* d_ws, size_t ws_size,
                              hipStream_t stream) {
    const float* X = (const float*)d_in[0];
    const float* Wq = (const float*)d_in[1];
    const float* Wk = (const float*)d_in[2];
    const float* Wv = (const float*)d_in[3];
    const float* Wo = (const float*)d_in[4];
    const float* RB = (const float*)d_in[5];

    char* ws = (char*)d_ws;
    size_t off = 0;
    auto alloc = [&](size_t bytes) {
        void* p = ws + off;
        off += (bytes + 255) & ~(size_t)255;
        return p;
    };
    short* X2 = (short*)alloc((size_t)8192 * 2048 * 2);
    short* WT2 = (short*)alloc((size_t)3072 * 2048 * 2);
    short* q2 = (short*)alloc((size_t)64 * 2048 * 128 * 2);
    short* k2 = (short*)alloc((size_t)64 * 2048 * 128 * 2);
    short* vt = (short*)alloc((size_t)64 * 64 * 2048 * 2);
    short* attn = (short*)alloc((size_t)8192 * 1024 * 2);
    short* WoT = (short*)alloc((size_t)1024 * 1024 * 2);
    short* btab = (short*)alloc((size_t)16 * 4096 * 2);

    xconv_kernel<<<8192, 256, 0, stream>>>(X, X2);
    wqkv_conv<<<dim3(32, 32, 3), dim3(32, 8), 0, stream>>>(Wq, Wk, Wv, WT2);
    wo_conv<<<dim3(32, 32), dim3(32, 8), 0, stream>>>(Wo, WoT);
    bias_kernel<<<256, 256, 0, stream>>>(RB, btab);
    // QKV projection: A=[Xhi|Xhi|Xlo] via aWrap, B=[Whi|Wlo|Whi] via bWrap, K'=3072
    // grid = 32 m-tiles x 12 n-tiles = 384 (%8==0 for XCD swizzle)
    gemm2<1><<<384, 512, 0, stream>>>(X2, WT2, 3072, 2048, 2048, 1024, 2048,
                                      nullptr, 0, q2, k2, vt);
    flash_kernel<<<512, 512, 0, stream>>>(q2, k2, vt, btab, attn);
    // Output projection: grid = 32 x 4 = 128
    gemm2<0><<<128, 512, 0, stream>>>(attn, WoT, 1024, 1024, 1024, 1 << 30, 1 << 30,
                                      (float*)d_out, 1024, nullptr, nullptr, nullptr);
}

// Round 7
// 504.423 us; speedup vs baseline: 1.1481x; 1.1481x over previous
//
#include <hip/hip_runtime.h>
#include <hip/hip_bf16.h>
#include <cstdint>

#define DI __device__ __forceinline__

typedef __attribute__((ext_vector_type(4))) float f32x4;
typedef __attribute__((ext_vector_type(16))) float f32x16;
typedef __attribute__((ext_vector_type(8))) short s16x8;
typedef __attribute__((ext_vector_type(4))) short s16x4;
typedef __attribute__((ext_vector_type(4))) unsigned int u32x4;
typedef unsigned int u32;

constexpr int Sc = 2048;
constexpr float LOG2E = 1.44269504088896340736f;
// B=4, D=1024, H=16, DK=64, M = B*S = 8192, BH = 64

DI short f2bf(float x) {
    __hip_bfloat16 h = __float2bfloat16(x);
    return __builtin_bit_cast(short, h);
}
DI float bf2f(short x) {
    __hip_bfloat16 h = __builtin_bit_cast(__hip_bfloat16, x);
    return __bfloat162float(h);
}
// pack two f32 -> dword of 2 bf16 (lo = a, hi = b) via verified scalar converts
DI u32 pack2(float a, float b) {
    return (u32)(unsigned short)f2bf(a) | ((u32)(unsigned short)f2bf(b) << 16);
}

// async 16B global -> LDS (dest = wave-uniform base + lane*16)
DI void cp16(const short* g, short* l) {
    __builtin_amdgcn_global_load_lds(
        (const __attribute__((address_space(1))) u32*)g,
        (__attribute__((address_space(3))) u32*)l, 16, 0, 0);
}

DI float fexp2(float x) {
#if __has_builtin(__builtin_amdgcn_exp2f)
    return __builtin_amdgcn_exp2f(x);
#else
    return exp2f(x);
#endif
}
DI float frcp(float x) {
#if __has_builtin(__builtin_amdgcn_rcpf)
    return __builtin_amdgcn_rcpf(x);
#else
    return 1.0f / x;
#endif
}

// ---- X [8192][1024] f32 -> X2 [8192][2048] bf16 : cols [0,1024)=hi, [1024,2048)=lo
__global__ void xconv_kernel(const float* __restrict__ X, short* __restrict__ X2) {
    size_t i = ((size_t)blockIdx.x * 256 + threadIdx.x) * 4;
    float4 v = *reinterpret_cast<const float4*>(X + i);
    int m = (int)(i >> 10);
    int k = (int)(i & 1023);
    float vv[4] = {v.x, v.y, v.z, v.w};
    short hi[4], lo[4];
#pragma unroll
    for (int j = 0; j < 4; ++j) { hi[j] = f2bf(vv[j]); lo[j] = f2bf(vv[j] - bf2f(hi[j])); }
    s16x4 h4 = {hi[0], hi[1], hi[2], hi[3]};
    s16x4 l4 = {lo[0], lo[1], lo[2], lo[3]};
    *reinterpret_cast<s16x4*>(X2 + (size_t)m * 2048 + k) = h4;
    *reinterpret_cast<s16x4*>(X2 + (size_t)m * 2048 + 1024 + k) = l4;
}

// ---- Wq/Wk/Wv [1024][1024] f32 -> WT2 [3072][2048] bf16 (transposed; [n][k]: hi at k, lo at 1024+k)
__global__ void wqkv_conv(const float* __restrict__ Wq, const float* __restrict__ Wk,
                          const float* __restrict__ Wv, short* __restrict__ WT2) {
    __shared__ float t[32][33];
    int z = blockIdx.z;
    const float* W = (z == 0) ? Wq : (z == 1 ? Wk : Wv);
    int k0 = blockIdx.x * 32, n0 = blockIdx.y * 32;
    int tx = threadIdx.x, ty = threadIdx.y;
#pragma unroll
    for (int i = 0; i < 4; ++i)
        t[ty + 8 * i][tx] = W[(size_t)(k0 + ty + 8 * i) * 1024 + n0 + tx];
    __syncthreads();
#pragma unroll
    for (int i = 0; i < 4; ++i) {
        float v = t[tx][ty + 8 * i];
        short hi = f2bf(v), lo = f2bf(v - bf2f(hi));
        size_t r = (size_t)(z * 1024 + n0 + ty + 8 * i) * 2048 + k0 + tx;
        WT2[r] = hi;
        WT2[r + 1024] = lo;
    }
}

// ---- Wo [1024][1024] f32 -> WoT [1024][1024] bf16 (transposed, hi only)
__global__ void wo_conv(const float* __restrict__ Wo, short* __restrict__ WoT) {
    __shared__ float t[32][33];
    int k0 = blockIdx.x * 32, n0 = blockIdx.y * 32;
    int tx = threadIdx.x, ty = threadIdx.y;
#pragma unroll
    for (int i = 0; i < 4; ++i)
        t[ty + 8 * i][tx] = Wo[(size_t)(k0 + ty + 8 * i) * 1024 + n0 + tx];
    __syncthreads();
#pragma unroll
    for (int i = 0; i < 4; ++i)
        WoT[(size_t)(n0 + ty + 8 * i) * 1024 + k0 + tx] = f2bf(t[tx][ty + 8 * i]);
}

// ---- bias table [16][4096] bf16, PRE-SCALED by log2(e): tab[h][delta+2047] = log2e*rel_bias[bucket][h]
// Exact integer thresholds equivalent to int(log(rel/8)/log(16)*8) under correctly-rounded log.
__global__ void bias_kernel(const float* __restrict__ rel_bias, short* __restrict__ tab) {
    int idx = blockIdx.x * 256 + threadIdx.x;  // 16*4096
    int h = idx >> 12;
    int i = idx & 4095;
    int delta = i - 2047;
    int ad = delta < 0 ? -delta : delta;
    int b;
    if (ad < 8) b = ad;
    else if (ad < 12) b = 8;
    else if (ad < 16) b = 9;
    else if (ad < 23) b = 10;
    else if (ad < 32) b = 11;
    else if (ad < 46) b = 12;
    else if (ad < 64) b = 13;
    else if (ad < 91) b = 14;
    else b = 15;
    if (delta > 0) b += 16;
    tab[idx] = f2bf(rel_bias[b * 16 + h] * LOG2E);
}

// ---- GEMM, pipelined: BM=128 x BN=256, BK=32, 256 threads = 4 waves, wave-tile 128x64
// (high MFMA:ds ratio: 32 MFMA per 12 ds_read_b128 per wave per tile).
// Triple-buffered LDS (72KB -> 2 blocks/CU), stage tile t+2 during tile t via
// global_load_lds with pre-swizzled global source (T2; linear LDS dest), counted
// s_waitcnt vmcnt(6) at tile boundaries (T4; 6 loads/thread/tile = 2A + 4B), setprio (T5).
// Correctness: per-thread VMEM FIFO -> at the boundary entering tile t+1, outstanding
// loads are exactly t+2's 6; vmcnt(6) retires everything older, so t+1's tile is
// LDS-resident after the barrier. Buf (t+2)%3 == (t-1)%3 went dead at the prior barrier
// (its ds_reads completed before the feeding MFMAs issued).
// Split-K' remap via aWrap/bWrap. EPI=0: fp32 C. EPI=1: Q'(log2e, hi|lo), K'(hi|lo), V^T.
template <int EPI>
__launch_bounds__(256, 2)
__global__ void gemm2(const short* __restrict__ A, const short* __restrict__ Bt,
                      int K, int lda, int ldb, int aWrap, int bWrap,
                      float* __restrict__ C, int ldc,
                      short* __restrict__ q2, short* __restrict__ k2, short* __restrict__ vt) {
    __shared__ __align__(16) short As[3][128 * 32];
    __shared__ __align__(16) short Bs[3][256 * 32];
    const int tid = threadIdx.x;
    const int w = tid >> 6, l = tid & 63;
    const int rl = l >> 4, cl = l & 15;

    // XCD-aware swizzle, m-fast decode (B panel stays hot in the XCD's L2; grid%8==0)
    const int cpx = gridDim.x >> 3;
    const int swz = ((int)blockIdx.x & 7) * cpx + ((int)blockIdx.x >> 3);
    const int m0 = (swz & 63) * 128;
    const int n0 = (swz >> 6) * 256;

    f32x4 acc[8][4];
#pragma unroll
    for (int i = 0; i < 8; ++i)
#pragma unroll
        for (int j = 0; j < 4; ++j) acc[i][j] = (f32x4){0.f, 0.f, 0.f, 0.f};

    const int NT = K / 32;
    // staging: per thread per tile 2 A-loads + 4 B-loads; source chunk pre-swizzled
    const int sr = tid >> 2;                       // local row (0..63 per j-group)
    const int scg = (tid & 3) ^ ((tid >> 3) & 3);  // swizzled source chunk (static)
    auto stageA = [&](int buf, int t, int j) {     // j=0,1 : rows j*64..j*64+63
        int kk = t * 32;
        int ca = kk - (kk >= aWrap ? aWrap : 0);
        cp16(A + (size_t)(m0 + j * 64 + sr) * lda + ca + scg * 8,
             &As[buf][(j * 256 + w * 64) * 8]);
    };
    auto stageB = [&](int buf, int t, int j) {     // j=0..3 : rows j*64..j*64+63
        int kk = t * 32;
        int cb = kk - (kk >= bWrap ? bWrap : 0);
        cp16(Bt + (size_t)(n0 + j * 64 + sr) * ldb + cb + scg * 8,
             &Bs[buf][(j * 256 + w * 64) * 8]);
    };

    // fragment reads: slot = rl ^ ((row>>1)&3); row-group offsets are ==0 mod 4,
    // so the XOR term reduces to (cl>>1)&3 -- static per lane.
    const int sl = (rl ^ ((cl >> 1) & 3)) * 8;
    const int abase = cl * 32 + sl;                // A-frag i at + i*512 (rows i*16+cl)
    const int bbase = (w * 64 + cl) * 32 + sl;     // B-frag ni at + ni*512

    // prologue: stage tiles 0 and 1 (6 loads each)
    stageA(0, 0, 0); stageA(0, 0, 1);
    stageB(0, 0, 0); stageB(0, 0, 1); stageB(0, 0, 2); stageB(0, 0, 3);
    stageA(1, 1, 0); stageA(1, 1, 1);
    stageB(1, 1, 0); stageB(1, 1, 1); stageB(1, 1, 2); stageB(1, 1, 3);
    asm volatile("s_waitcnt vmcnt(6)" ::: "memory");
    __builtin_amdgcn_s_barrier();

    for (int t = 0; t < NT; ++t) {
        const int buf = t % 3;
        const int sbuf = (t + 2) % 3;
        const bool dost = (t + 2) < NT;

        // issue next-next tile's loads first (they hide under this tile's compute)
        if (dost) {
            stageA(sbuf, t + 2, 0); stageA(sbuf, t + 2, 1);
            stageB(sbuf, t + 2, 0); stageB(sbuf, t + 2, 1);
            stageB(sbuf, t + 2, 2); stageB(sbuf, t + 2, 3);
        }

        const short* Ab = &As[buf][abase];
        const short* Bb = &Bs[buf][bbase];
        s16x8 bfv[4], af[8];
#pragma unroll
        for (int ni = 0; ni < 4; ++ni)
            bfv[ni] = *reinterpret_cast<const s16x8*>(Bb + ni * 512);
#pragma unroll
        for (int i = 0; i < 8; ++i)
            af[i] = *reinterpret_cast<const s16x8*>(Ab + i * 512);

        __builtin_amdgcn_s_setprio(1);
#pragma unroll
        for (int i = 0; i < 8; ++i)
#pragma unroll
            for (int ni = 0; ni < 4; ++ni)
                acc[i][ni] = __builtin_amdgcn_mfma_f32_16x16x32_bf16(af[i], bfv[ni], acc[i][ni], 0, 0, 0);
        __builtin_amdgcn_s_setprio(0);

        if (t + 1 < NT) {
            if (dost) asm volatile("s_waitcnt vmcnt(6)" ::: "memory");
            else      asm volatile("s_waitcnt vmcnt(0)" ::: "memory");
            __builtin_amdgcn_s_barrier();
        }
    }

    if (EPI == 0) {
#pragma unroll
        for (int mi = 0; mi < 8; ++mi) {
            int row = m0 + mi * 16 + rl * 4;
#pragma unroll
            for (int ni = 0; ni < 4; ++ni) {
                int col = n0 + w * 64 + ni * 16 + cl;
#pragma unroll
                for (int r = 0; r < 4; ++r)
                    C[(size_t)(row + r) * ldc + col] = acc[mi][ni][r];
            }
        }
    } else {
        int region = n0 >> 10;  // block-uniform: 0=Q 1=K 2=V
#pragma unroll
        for (int mi = 0; mi < 8; ++mi) {
#pragma unroll
            for (int ni = 0; ni < 4; ++ni) {
#pragma unroll
                for (int r = 0; r < 4; ++r) {
                    int m = m0 + mi * 16 + rl * 4 + r;
                    int n = (n0 & 1023) + w * 64 + ni * 16 + cl;
                    int bb = m >> 11, s = m & 2047;
                    int h = n >> 6, d = n & 63;
                    int bh = bb * 16 + h;
                    float c = acc[mi][ni][r];
                    if (region == 0) {
                        c *= LOG2E;  // fold softmax base-2 conversion into Q
                        short hi = f2bf(c);
                        short lo = f2bf(c - bf2f(hi));
                        size_t base = ((size_t)bh * 2048 + s) * 128;
                        q2[base + d] = hi;
                        q2[base + 64 + d] = lo;
                    } else if (region == 1) {
                        short hi = f2bf(c);
                        short lo = f2bf(c - bf2f(hi));
                        size_t base = ((size_t)bh * 2048 + s) * 128;
                        k2[base + d] = hi;
                        k2[base + 64 + d] = lo;
                    } else {
                        vt[((size_t)bh * 64 + d) * 2048 + s] = f2bf(c);
                    }
                }
            }
        }
    }
}

// ---- Flash attention, 32x32 swapped-operand form (validated r5).
// Grid: 512 blocks (XCD-swizzled), 512 threads = 8 waves; wave owns 32 q-rows (q-block 256).
// Swapped QK: mfma(A=K', B=Q') -> lane holds 16 scores of ONE q-row (q = lane&31).
// P stays in registers; cross-half exchange via verified __shfl_xor(32) + select.
// No online max (|score*log2e| < ~90 << 127, exp2/fp32-sum safe); psum is in-lane scalar.
__launch_bounds__(512, 4)
__global__ void flash_kernel(const short* __restrict__ q2, const short* __restrict__ k2,
                             const short* __restrict__ vt, const short* __restrict__ btab,
                             short* __restrict__ attnb) {
    __shared__ __align__(16) short Ks[2][8192];   // [buf] 64 rows x 16 chunks(16B), slot = c ^ (r&15)
    __shared__ __align__(16) short Vs[2][4096];   // [buf] 64 d-rows x 8 chunks, slot = c ^ (d&7)
    __shared__ __align__(16) short Bsh[2304];     // bias slice (bf16, log2e-scaled)

    const int tid = threadIdx.x;
    const int w = tid >> 6, l = tid & 63;
    const int l31 = l & 31, hi = l >> 5;

    const int L = blockIdx.x;
    const int xcd = L & 7, idx = L >> 3;
    const int bh = xcd + 8 * (idx & 7);
    const int qb = idx >> 3;
    const int h = bh & 15;
    const int q0b = qb * 256;
    const int qw0 = q0b + w * 32;
    const int qL = w * 32 + l31;

    const short* Q = q2 + (size_t)bh * Sc * 128;
    const short* Kp = k2 + (size_t)bh * Sc * 128;
    const short* V = vt + (size_t)bh * 64 * Sc;

    {
        int base = h * 4096 + 1792 - q0b;
        for (int i = tid; i < 2304; i += 512) Bsh[i] = btab[base + i];
    }

    auto stage = [&](int buf, int it2) {
        int kv0 = it2 * 64;
#pragma unroll
        for (int j = 0; j < 2; ++j) {
            int o = w * 128 + j * 64 + l;
            int r = o >> 4, cs = o & 15;
            int cg = cs ^ (r & 15);
            cp16(Kp + (size_t)(kv0 + r) * 128 + cg * 8, &Ks[buf][(w * 128 + j * 64) * 8]);
        }
        {
            int o = w * 64 + l;
            int d = o >> 3, cs = o & 7;
            int cg = cs ^ (d & 7);
            cp16(V + (size_t)d * 2048 + kv0 + cg * 8, &Vs[buf][(w * 64) * 8]);
        }
    };

    s16x8 qf[8];
#pragma unroll
    for (int c = 0; c < 8; ++c)
        qf[c] = *reinterpret_cast<const s16x8*>(Q + (size_t)(qw0 + l31) * 128 + c * 16 + hi * 8);

    f32x16 accO[2];
#pragma unroll
    for (int i = 0; i < 16; ++i) { accO[0][i] = 0.f; accO[1][i] = 0.f; }
    float psum = 0.f;

    stage(0, 0);
    __syncthreads();

    for (int it = 0; it < 32; ++it) {
        const int cur = it & 1;
        if (it + 1 < 32) stage(cur ^ 1, it + 1);
        const int kv0 = it * 64;
#pragma unroll
        for (int T = 0; T < 2; ++T) {
            const int rA = T * 32 + l31;
            const int rsw = rA & 15;
            const short* kbase = &Ks[cur][rA * 128];
            s16x8 kh[4];
#pragma unroll
            for (int c = 0; c < 4; ++c)
                kh[c] = *reinterpret_cast<const s16x8*>(kbase + ((c * 2 + hi) ^ rsw) * 8);
            f32x16 acc = {0.f,0.f,0.f,0.f,0.f,0.f,0.f,0.f,0.f,0.f,0.f,0.f,0.f,0.f,0.f,0.f};
#pragma unroll
            for (int c = 0; c < 4; ++c)
                acc = __builtin_amdgcn_mfma_f32_32x32x16_bf16(kh[c], qf[c], acc, 0, 0, 0);
#pragma unroll
            for (int c = 0; c < 4; ++c)
                acc = __builtin_amdgcn_mfma_f32_32x32x16_bf16(kh[c], qf[c + 4], acc, 0, 0, 0);
#pragma unroll
            for (int c = 0; c < 4; ++c) {
                s16x8 klo = *reinterpret_cast<const s16x8*>(kbase + (((c + 4) * 2 + hi) ^ rsw) * 8);
                acc = __builtin_amdgcn_mfma_f32_32x32x16_bf16(klo, qf[c], acc, 0, 0, 0);
            }
#pragma unroll
            for (int t2 = 0; t2 < 2; ++t2) {
                u32 pk[4];
#pragma unroll
                for (int i = 0; i < 4; ++i) {
                    const int ii = t2 * 4 + i;
                    const int pstart = ((ii & 1) * 2) + ((ii >> 1) * 8);
                    const int kvg = kv0 + T * 32 + pstart + 4 * hi;
                    const int i0 = kvg - qL + 255;
                    const float b0 = bf2f(Bsh[i0]);
                    const float b1 = bf2f(Bsh[i0 + 1]);
                    const int r0 = t2 * 8 + i * 2;
                    const float e0 = fexp2(acc[r0] + b0);
                    const float e1 = fexp2(acc[r0 + 1] + b1);
                    psum += e0 + e1;
                    pk[i] = pack2(e0, e1);
                }
                const u32 ex0 = __shfl_xor(pk[0], 32);
                const u32 ex1 = __shfl_xor(pk[1], 32);
                const u32 ex2 = __shfl_xor(pk[2], 32);
                const u32 ex3 = __shfl_xor(pk[3], 32);
                const u32 d0 = hi ? ex2 : pk[0];
                const u32 d1 = hi ? ex3 : pk[1];
                const u32 d2 = hi ? pk[2] : ex0;
                const u32 d3 = hi ? pk[3] : ex1;
                u32x4 pv4 = {d0, d1, d2, d3};
                s16x8 pfrag = __builtin_bit_cast(s16x8, pv4);
                const int tg = T * 2 + t2;
#pragma unroll
                for (int dt = 0; dt < 2; ++dt) {
                    const int d = dt * 32 + l31;
                    s16x8 vf = *reinterpret_cast<const s16x8*>(
                        &Vs[cur][d * 64 + ((tg * 2 + hi) ^ (d & 7)) * 8]);
                    accO[dt] = __builtin_amdgcn_mfma_f32_32x32x16_bf16(pfrag, vf, accO[dt], 0, 0, 0);
                }
            }
        }
        __syncthreads();
    }

    psum += __shfl_xor(psum, 32);

    const int bb = bh >> 4;
#pragma unroll
    for (int r = 0; r < 16; ++r) {
        const int qloc = (r & 3) + 8 * (r >> 2) + 4 * hi;
        const float inv = frcp(__shfl(psum, qloc));
        const size_t rowbase = ((size_t)(bb * 2048 + qw0 + qloc)) * 1024 + h * 64;
#pragma unroll
        for (int dt = 0; dt < 2; ++dt)
            attnb[rowbase + dt * 32 + l31] = f2bf(accO[dt][r] * inv);
    }
}

extern "C" void kernel_launch(void* const* d_in, const int* in_sizes, int n_in,
                              void* d_out, int out_size, void* d_ws, size_t ws_size,
                              hipStream_t stream) {
    const float* X = (const float*)d_in[0];
    const float* Wq = (const float*)d_in[1];
    const float* Wk = (const float*)d_in[2];
    const float* Wv = (const float*)d_in[3];
    const float* Wo = (const float*)d_in[4];
    const float* RB = (const float*)d_in[5];

    char* ws = (char*)d_ws;
    size_t off = 0;
    auto alloc = [&](size_t bytes) {
        void* p = ws + off;
        off += (bytes + 255) & ~(size_t)255;
        return p;
    };
    short* X2 = (short*)alloc((size_t)8192 * 2048 * 2);
    short* WT2 = (short*)alloc((size_t)3072 * 2048 * 2);
    short* q2 = (short*)alloc((size_t)64 * 2048 * 128 * 2);
    short* k2 = (short*)alloc((size_t)64 * 2048 * 128 * 2);
    short* vt = (short*)alloc((size_t)64 * 64 * 2048 * 2);
    short* attn = (short*)alloc((size_t)8192 * 1024 * 2);
    short* WoT = (short*)alloc((size_t)1024 * 1024 * 2);
    short* btab = (short*)alloc((size_t)16 * 4096 * 2);

    xconv_kernel<<<8192, 256, 0, stream>>>(X, X2);
    wqkv_conv<<<dim3(32, 32, 3), dim3(32, 8), 0, stream>>>(Wq, Wk, Wv, WT2);
    wo_conv<<<dim3(32, 32), dim3(32, 8), 0, stream>>>(Wo, WoT);
    bias_kernel<<<256, 256, 0, stream>>>(RB, btab);
    // QKV projection: A=[Xhi|Xhi|Xlo] via aWrap, B=[Whi|Wlo|Whi] via bWrap, K'=3072
    // grid = 64 m-tiles x 12 n-tiles = 768 (= 3 blocks/CU exactly, %8==0 for XCD swizzle)
    gemm2<1><<<768, 256, 0, stream>>>(X2, WT2, 3072, 2048, 2048, 1024, 2048,
                                      nullptr, 0, q2, k2, vt);
    flash_kernel<<<512, 512, 0, stream>>>(q2, k2, vt, btab, attn);
    // Output projection: grid = 64 x 4 = 256
    gemm2<0><<<256, 256, 0, stream>>>(attn, WoT, 1024, 1024, 1024, 1 << 30, 1 << 30,
                                      (float*)d_out, 1024, nullptr, nullptr, nullptr);
}

// Round 8
// 431.848 us; speedup vs baseline: 1.3411x; 1.1681x over previous
//
#include <hip/hip_runtime.h>
#include <hip/hip_bf16.h>
#include <cstdint>

#define DI __device__ __forceinline__

typedef __attribute__((ext_vector_type(4))) float f32x4;
typedef __attribute__((ext_vector_type(16))) float f32x16;
typedef __attribute__((ext_vector_type(8))) short s16x8;
typedef __attribute__((ext_vector_type(4))) short s16x4;
typedef __attribute__((ext_vector_type(4))) unsigned int u32x4;
typedef unsigned int u32;

constexpr int Sc = 2048;
constexpr float LOG2E = 1.44269504088896340736f;
// B=4, D=1024, H=16, DK=64, M = B*S = 8192, BH = 64

DI short f2bf(float x) {
    __hip_bfloat16 h = __float2bfloat16(x);
    return __builtin_bit_cast(short, h);
}
DI float bf2f(short x) {
    __hip_bfloat16 h = __builtin_bit_cast(__hip_bfloat16, x);
    return __bfloat162float(h);
}
// pack two f32 -> dword of 2 bf16 (lo = a, hi = b) via verified scalar converts
DI u32 pack2(float a, float b) {
    return (u32)(unsigned short)f2bf(a) | ((u32)(unsigned short)f2bf(b) << 16);
}

// async 16B global -> LDS (dest = wave-uniform base + lane*16)
DI void cp16(const short* g, short* l) {
    __builtin_amdgcn_global_load_lds(
        (const __attribute__((address_space(1))) u32*)g,
        (__attribute__((address_space(3))) u32*)l, 16, 0, 0);
}

DI float fexp2(float x) {
#if __has_builtin(__builtin_amdgcn_exp2f)
    return __builtin_amdgcn_exp2f(x);
#else
    return exp2f(x);
#endif
}
DI float frcp(float x) {
#if __has_builtin(__builtin_amdgcn_rcpf)
    return __builtin_amdgcn_rcpf(x);
#else
    return 1.0f / x;
#endif
}

// ---- X [8192][1024] f32 -> X2 [8192][2048] bf16 : cols [0,1024)=hi, [1024,2048)=lo
__global__ void xconv_kernel(const float* __restrict__ X, short* __restrict__ X2) {
    size_t i = ((size_t)blockIdx.x * 256 + threadIdx.x) * 4;
    float4 v = *reinterpret_cast<const float4*>(X + i);
    int m = (int)(i >> 10);
    int k = (int)(i & 1023);
    float vv[4] = {v.x, v.y, v.z, v.w};
    short hi[4], lo[4];
#pragma unroll
    for (int j = 0; j < 4; ++j) { hi[j] = f2bf(vv[j]); lo[j] = f2bf(vv[j] - bf2f(hi[j])); }
    s16x4 h4 = {hi[0], hi[1], hi[2], hi[3]};
    s16x4 l4 = {lo[0], lo[1], lo[2], lo[3]};
    *reinterpret_cast<s16x4*>(X2 + (size_t)m * 2048 + k) = h4;
    *reinterpret_cast<s16x4*>(X2 + (size_t)m * 2048 + 1024 + k) = l4;
}

// ---- Wq/Wk/Wv [1024][1024] f32 -> WT2 [3072][2048] bf16 (transposed; [n][k]: hi at k, lo at 1024+k)
__global__ void wqkv_conv(const float* __restrict__ Wq, const float* __restrict__ Wk,
                          const float* __restrict__ Wv, short* __restrict__ WT2) {
    __shared__ float t[32][33];
    int z = blockIdx.z;
    const float* W = (z == 0) ? Wq : (z == 1 ? Wk : Wv);
    int k0 = blockIdx.x * 32, n0 = blockIdx.y * 32;
    int tx = threadIdx.x, ty = threadIdx.y;
#pragma unroll
    for (int i = 0; i < 4; ++i)
        t[ty + 8 * i][tx] = W[(size_t)(k0 + ty + 8 * i) * 1024 + n0 + tx];
    __syncthreads();
#pragma unroll
    for (int i = 0; i < 4; ++i) {
        float v = t[tx][ty + 8 * i];
        short hi = f2bf(v), lo = f2bf(v - bf2f(hi));
        size_t r = (size_t)(z * 1024 + n0 + ty + 8 * i) * 2048 + k0 + tx;
        WT2[r] = hi;
        WT2[r + 1024] = lo;
    }
}

// ---- Wo [1024][1024] f32 -> WoT [1024][1024] bf16 (transposed, hi only)
__global__ void wo_conv(const float* __restrict__ Wo, short* __restrict__ WoT) {
    __shared__ float t[32][33];
    int k0 = blockIdx.x * 32, n0 = blockIdx.y * 32;
    int tx = threadIdx.x, ty = threadIdx.y;
#pragma unroll
    for (int i = 0; i < 4; ++i)
        t[ty + 8 * i][tx] = Wo[(size_t)(k0 + ty + 8 * i) * 1024 + n0 + tx];
    __syncthreads();
#pragma unroll
    for (int i = 0; i < 4; ++i)
        WoT[(size_t)(n0 + ty + 8 * i) * 1024 + k0 + tx] = f2bf(t[tx][ty + 8 * i]);
}

// ---- bias table [16][4096] bf16, PRE-SCALED by log2(e): tab[h][delta+2047] = log2e*rel_bias[bucket][h]
// Exact integer thresholds equivalent to int(log(rel/8)/log(16)*8) under correctly-rounded log.
__global__ void bias_kernel(const float* __restrict__ rel_bias, short* __restrict__ tab) {
    int idx = blockIdx.x * 256 + threadIdx.x;  // 16*4096
    int h = idx >> 12;
    int i = idx & 4095;
    int delta = i - 2047;
    int ad = delta < 0 ? -delta : delta;
    int b;
    if (ad < 8) b = ad;
    else if (ad < 12) b = 8;
    else if (ad < 16) b = 9;
    else if (ad < 23) b = 10;
    else if (ad < 32) b = 11;
    else if (ad < 46) b = 12;
    else if (ad < 64) b = 13;
    else if (ad < 91) b = 14;
    else b = 15;
    if (delta > 0) b += 16;
    tab[idx] = f2bf(rel_bias[b * 16 + h] * LOG2E);
}

// ---- GEMM (proven r5 m97-structure): C[M,N] = A[M,K'] * B[K',N], B given as B^T [N][K'].
// global_load_lds staging, single LDS buffer, 2 barriers per K-step.
// Split-K' remap: colA = kk - (kk>=aWrap ? aWrap : 0), same for B.
// EPI=0: fp32 C.  EPI=1 (QK): Q'(log2e, hi|lo) and K'(hi|lo).  EPI=2 (V): V^T bf16.
template <int EPI>
__launch_bounds__(256)
__global__ void gemm_bt(const short* __restrict__ A, const short* __restrict__ Bt,
                        int K, int lda, int ldb, int aWrap, int bWrap,
                        float* __restrict__ C, int ldc,
                        short* __restrict__ q2, short* __restrict__ k2, short* __restrict__ vt) {
    __shared__ __align__(16) short As[128 * 32];
    __shared__ __align__(16) short Bs[128 * 32];
    const int tid = threadIdx.x;
    const int w = tid >> 6, l = tid & 63;
    const int m0 = blockIdx.x * 128, n0 = blockIdx.y * 128;
    const int wm = (w >> 1) * 64, wn = (w & 1) * 64;
    const int ar = tid >> 2, ac = (tid & 3) * 8;
    const int wb = w * 512;

    f32x4 acc[4][4];
#pragma unroll
    for (int i = 0; i < 4; ++i)
#pragma unroll
        for (int j = 0; j < 4; ++j) acc[i][j] = (f32x4){0.f, 0.f, 0.f, 0.f};

    const int nk = K / 32;
    for (int kt = 0; kt < nk; ++kt) {
        int kk = kt * 32;
        int ca = kk - (kk >= aWrap ? aWrap : 0);
        int cb = kk - (kk >= bWrap ? bWrap : 0);
        cp16(A + (size_t)(m0 + ar) * lda + ca + ac, As + wb);
        cp16(A + (size_t)(m0 + 64 + ar) * lda + ca + ac, As + 2048 + wb);
        cp16(Bt + (size_t)(n0 + ar) * ldb + cb + ac, Bs + wb);
        cp16(Bt + (size_t)(n0 + 64 + ar) * ldb + cb + ac, Bs + 2048 + wb);
        __syncthreads();
        s16x8 af[4], bfv[4];
#pragma unroll
        for (int i = 0; i < 4; ++i)
            af[i] = *reinterpret_cast<const s16x8*>(As + (wm + i * 16 + (l & 15)) * 32 + (l >> 4) * 8);
#pragma unroll
        for (int i = 0; i < 4; ++i)
            bfv[i] = *reinterpret_cast<const s16x8*>(Bs + (wn + i * 16 + (l & 15)) * 32 + (l >> 4) * 8);
#pragma unroll
        for (int mi = 0; mi < 4; ++mi)
#pragma unroll
            for (int ni = 0; ni < 4; ++ni)
                acc[mi][ni] = __builtin_amdgcn_mfma_f32_16x16x32_bf16(af[mi], bfv[ni], acc[mi][ni], 0, 0, 0);
        __syncthreads();
    }

    const int rl = l >> 4, cl = l & 15;
    if (EPI == 0) {
#pragma unroll
        for (int mi = 0; mi < 4; ++mi) {
            int row = m0 + wm + mi * 16 + rl * 4;
#pragma unroll
            for (int ni = 0; ni < 4; ++ni) {
                int col = n0 + wn + ni * 16 + cl;
#pragma unroll
                for (int r = 0; r < 4; ++r)
                    C[(size_t)(row + r) * ldc + col] = acc[mi][ni][r];
            }
        }
    } else if (EPI == 1) {
        int region = n0 >> 10;  // block-uniform: 0=Q 1=K
#pragma unroll
        for (int mi = 0; mi < 4; ++mi) {
#pragma unroll
            for (int ni = 0; ni < 4; ++ni) {
#pragma unroll
                for (int r = 0; r < 4; ++r) {
                    int m = m0 + wm + mi * 16 + rl * 4 + r;
                    int n = (n0 & 1023) + wn + ni * 16 + cl;
                    int bb = m >> 11, s = m & 2047;
                    int h = n >> 6, d = n & 63;
                    int bh = bb * 16 + h;
                    float c = acc[mi][ni][r];
                    if (region == 0) {
                        c *= LOG2E;  // fold softmax base-2 conversion into Q
                        short hi = f2bf(c);
                        short lo = f2bf(c - bf2f(hi));
                        size_t base = ((size_t)bh * 2048 + s) * 128;
                        q2[base + d] = hi;
                        q2[base + 64 + d] = lo;
                    } else {
                        short hi = f2bf(c);
                        short lo = f2bf(c - bf2f(hi));
                        size_t base = ((size_t)bh * 2048 + s) * 128;
                        k2[base + d] = hi;
                        k2[base + 64 + d] = lo;
                    }
                }
            }
        }
    } else {  // EPI == 2: V^T epilogue (single-bf16 V projection)
#pragma unroll
        for (int mi = 0; mi < 4; ++mi) {
#pragma unroll
            for (int ni = 0; ni < 4; ++ni) {
#pragma unroll
                for (int r = 0; r < 4; ++r) {
                    int m = m0 + wm + mi * 16 + rl * 4 + r;
                    int n = n0 + wn + ni * 16 + cl;  // n in [0,1024)
                    int bb = m >> 11, s = m & 2047;
                    int h = n >> 6, d = n & 63;
                    int bh = bb * 16 + h;
                    vt[((size_t)bh * 64 + d) * 2048 + s] = f2bf(acc[mi][ni][r]);
                }
            }
        }
    }
}

// ---- Flash attention, 32x32 swapped-operand form (validated r5).
// Grid: 512 blocks (XCD-swizzled), 512 threads = 8 waves; wave owns 32 q-rows (q-block 256).
// Swapped QK: mfma(A=K', B=Q') -> lane holds 16 scores of ONE q-row (q = lane&31).
// P stays in registers; cross-half exchange via verified __shfl_xor(32) + select.
// No online max (|score*log2e| < ~90 << 127, exp2/fp32-sum safe); psum is in-lane scalar.
__launch_bounds__(512, 4)
__global__ void flash_kernel(const short* __restrict__ q2, const short* __restrict__ k2,
                             const short* __restrict__ vt, const short* __restrict__ btab,
                             short* __restrict__ attnb) {
    __shared__ __align__(16) short Ks[2][8192];   // [buf] 64 rows x 16 chunks(16B), slot = c ^ (r&15)
    __shared__ __align__(16) short Vs[2][4096];   // [buf] 64 d-rows x 8 chunks, slot = c ^ (d&7)
    __shared__ __align__(16) short Bsh[2304];     // bias slice (bf16, log2e-scaled)

    const int tid = threadIdx.x;
    const int w = tid >> 6, l = tid & 63;
    const int l31 = l & 31, hi = l >> 5;

    const int L = blockIdx.x;
    const int xcd = L & 7, idx = L >> 3;
    const int bh = xcd + 8 * (idx & 7);
    const int qb = idx >> 3;
    const int h = bh & 15;
    const int q0b = qb * 256;
    const int qw0 = q0b + w * 32;
    const int qL = w * 32 + l31;

    const short* Q = q2 + (size_t)bh * Sc * 128;
    const short* Kp = k2 + (size_t)bh * Sc * 128;
    const short* V = vt + (size_t)bh * 64 * Sc;

    {
        int base = h * 4096 + 1792 - q0b;
        for (int i = tid; i < 2304; i += 512) Bsh[i] = btab[base + i];
    }

    auto stage = [&](int buf, int it2) {
        int kv0 = it2 * 64;
#pragma unroll
        for (int j = 0; j < 2; ++j) {
            int o = w * 128 + j * 64 + l;
            int r = o >> 4, cs = o & 15;
            int cg = cs ^ (r & 15);
            cp16(Kp + (size_t)(kv0 + r) * 128 + cg * 8, &Ks[buf][(w * 128 + j * 64) * 8]);
        }
        {
            int o = w * 64 + l;
            int d = o >> 3, cs = o & 7;
            int cg = cs ^ (d & 7);
            cp16(V + (size_t)d * 2048 + kv0 + cg * 8, &Vs[buf][(w * 64) * 8]);
        }
    };

    s16x8 qf[8];
#pragma unroll
    for (int c = 0; c < 8; ++c)
        qf[c] = *reinterpret_cast<const s16x8*>(Q + (size_t)(qw0 + l31) * 128 + c * 16 + hi * 8);

    f32x16 accO[2];
#pragma unroll
    for (int i = 0; i < 16; ++i) { accO[0][i] = 0.f; accO[1][i] = 0.f; }
    float psum = 0.f;

    stage(0, 0);
    __syncthreads();

    for (int it = 0; it < 32; ++it) {
        const int cur = it & 1;
        if (it + 1 < 32) stage(cur ^ 1, it + 1);
        const int kv0 = it * 64;
#pragma unroll
        for (int T = 0; T < 2; ++T) {
            const int rA = T * 32 + l31;
            const int rsw = rA & 15;
            const short* kbase = &Ks[cur][rA * 128];
            s16x8 kh[4];
#pragma unroll
            for (int c = 0; c < 4; ++c)
                kh[c] = *reinterpret_cast<const s16x8*>(kbase + ((c * 2 + hi) ^ rsw) * 8);
            f32x16 acc = {0.f,0.f,0.f,0.f,0.f,0.f,0.f,0.f,0.f,0.f,0.f,0.f,0.f,0.f,0.f,0.f};
#pragma unroll
            for (int c = 0; c < 4; ++c)
                acc = __builtin_amdgcn_mfma_f32_32x32x16_bf16(kh[c], qf[c], acc, 0, 0, 0);
#pragma unroll
            for (int c = 0; c < 4; ++c)
                acc = __builtin_amdgcn_mfma_f32_32x32x16_bf16(kh[c], qf[c + 4], acc, 0, 0, 0);
#pragma unroll
            for (int c = 0; c < 4; ++c) {
                s16x8 klo = *reinterpret_cast<const s16x8*>(kbase + (((c + 4) * 2 + hi) ^ rsw) * 8);
                acc = __builtin_amdgcn_mfma_f32_32x32x16_bf16(klo, qf[c], acc, 0, 0, 0);
            }
#pragma unroll
            for (int t2 = 0; t2 < 2; ++t2) {
                u32 pk[4];
#pragma unroll
                for (int i = 0; i < 4; ++i) {
                    const int ii = t2 * 4 + i;
                    const int pstart = ((ii & 1) * 2) + ((ii >> 1) * 8);
                    const int kvg = kv0 + T * 32 + pstart + 4 * hi;
                    const int i0 = kvg - qL + 255;
                    const float b0 = bf2f(Bsh[i0]);
                    const float b1 = bf2f(Bsh[i0 + 1]);
                    const int r0 = t2 * 8 + i * 2;
                    const float e0 = fexp2(acc[r0] + b0);
                    const float e1 = fexp2(acc[r0 + 1] + b1);
                    psum += e0 + e1;
                    pk[i] = pack2(e0, e1);
                }
                const u32 ex0 = __shfl_xor(pk[0], 32);
                const u32 ex1 = __shfl_xor(pk[1], 32);
                const u32 ex2 = __shfl_xor(pk[2], 32);
                const u32 ex3 = __shfl_xor(pk[3], 32);
                const u32 d0 = hi ? ex2 : pk[0];
                const u32 d1 = hi ? ex3 : pk[1];
                const u32 d2 = hi ? pk[2] : ex0;
                const u32 d3 = hi ? pk[3] : ex1;
                u32x4 pv4 = {d0, d1, d2, d3};
                s16x8 pfrag = __builtin_bit_cast(s16x8, pv4);
                const int tg = T * 2 + t2;
#pragma unroll
                for (int dt = 0; dt < 2; ++dt) {
                    const int d = dt * 32 + l31;
                    s16x8 vf = *reinterpret_cast<const s16x8*>(
                        &Vs[cur][d * 64 + ((tg * 2 + hi) ^ (d & 7)) * 8]);
                    accO[dt] = __builtin_amdgcn_mfma_f32_32x32x16_bf16(pfrag, vf, accO[dt], 0, 0, 0);
                }
            }
        }
        __syncthreads();
    }

    psum += __shfl_xor(psum, 32);

    const int bb = bh >> 4;
#pragma unroll
    for (int r = 0; r < 16; ++r) {
        const int qloc = (r & 3) + 8 * (r >> 2) + 4 * hi;
        const float inv = frcp(__shfl(psum, qloc));
        const size_t rowbase = ((size_t)(bb * 2048 + qw0 + qloc)) * 1024 + h * 64;
#pragma unroll
        for (int dt = 0; dt < 2; ++dt)
            attnb[rowbase + dt * 32 + l31] = f2bf(accO[dt][r] * inv);
    }
}

extern "C" void kernel_launch(void* const* d_in, const int* in_sizes, int n_in,
                              void* d_out, int out_size, void* d_ws, size_t ws_size,
                              hipStream_t stream) {
    const float* X = (const float*)d_in[0];
    const float* Wq = (const float*)d_in[1];
    const float* Wk = (const float*)d_in[2];
    const float* Wv = (const float*)d_in[3];
    const float* Wo = (const float*)d_in[4];
    const float* RB = (const float*)d_in[5];

    char* ws = (char*)d_ws;
    size_t off = 0;
    auto alloc = [&](size_t bytes) {
        void* p = ws + off;
        off += (bytes + 255) & ~(size_t)255;
        return p;
    };
    short* X2 = (short*)alloc((size_t)8192 * 2048 * 2);
    short* WT2 = (short*)alloc((size_t)3072 * 2048 * 2);
    short* q2 = (short*)alloc((size_t)64 * 2048 * 128 * 2);
    short* k2 = (short*)alloc((size_t)64 * 2048 * 128 * 2);
    short* vt = (short*)alloc((size_t)64 * 64 * 2048 * 2);
    short* attn = (short*)alloc((size_t)8192 * 1024 * 2);
    short* WoT = (short*)alloc((size_t)1024 * 1024 * 2);
    short* btab = (short*)alloc((size_t)16 * 4096 * 2);

    xconv_kernel<<<8192, 256, 0, stream>>>(X, X2);
    wqkv_conv<<<dim3(32, 32, 3), dim3(32, 8), 0, stream>>>(Wq, Wk, Wv, WT2);
    wo_conv<<<dim3(32, 32), dim3(32, 8), 0, stream>>>(Wo, WoT);
    bias_kernel<<<256, 256, 0, stream>>>(RB, btab);
    // QK projection (3-term split, K'=3072): A=[Xhi|Xhi|Xlo] via aWrap, B=[Whi|Wlo|Whi] via bWrap
    gemm_bt<1><<<dim3(64, 16), 256, 0, stream>>>(X2, WT2, 3072, 2048, 2048, 1024, 2048,
                                                 nullptr, 0, q2, k2, nullptr);
    // V projection (single bf16, K=1024): A=Xhi, B=Wv^T hi rows (WT2 rows 2048..3071)
    gemm_bt<2><<<dim3(64, 8), 256, 0, stream>>>(X2, WT2 + (size_t)2048 * 2048, 1024, 2048, 2048,
                                                1 << 30, 1 << 30, nullptr, 0, nullptr, nullptr, vt);
    flash_kernel<<<512, 512, 0, stream>>>(q2, k2, vt, btab, attn);
    // Output projection (single bf16)
    gemm_bt<0><<<dim3(64, 8), 256, 0, stream>>>(attn, WoT, 1024, 1024, 1024, 1 << 30, 1 << 30,
                                                (float*)d_out, 1024, nullptr, nullptr, nullptr);
}

// Round 10
// 402.439 us; speedup vs baseline: 1.4391x; 1.0731x over previous
//
#include <hip/hip_runtime.h>
#include <hip/hip_bf16.h>
#include <cstdint>

#define DI __device__ __forceinline__

typedef __attribute__((ext_vector_type(4))) float f32x4;
typedef __attribute__((ext_vector_type(16))) float f32x16;
typedef __attribute__((ext_vector_type(8))) short s16x8;
typedef __attribute__((ext_vector_type(4))) short s16x4;
typedef __attribute__((ext_vector_type(4))) unsigned int u32x4;
typedef unsigned int u32;

constexpr int Sc = 2048;
constexpr float LOG2E = 1.44269504088896340736f;
// B=4, D=1024, H=16, DK=64, M = B*S = 8192, BH = 64

DI short f2bf(float x) {
    __hip_bfloat16 h = __float2bfloat16(x);
    return __builtin_bit_cast(short, h);
}
DI float bf2f(short x) {
    __hip_bfloat16 h = __builtin_bit_cast(__hip_bfloat16, x);
    return __bfloat162float(h);
}
// pack two f32 -> dword of 2 bf16 (lo = a, hi = b) via verified scalar converts
DI u32 pack2(float a, float b) {
    return (u32)(unsigned short)f2bf(a) | ((u32)(unsigned short)f2bf(b) << 16);
}
// swap rows: a' = [a.row0, b.row0]; b' = [a.row1, b.row1]  (rows = 32-lane halves)
DI void pl32swap(u32& a, u32& b) {
    asm("v_permlane32_swap_b32 %0, %1" : "+v"(a), "+v"(b));
}

// async 16B global -> LDS (dest = wave-uniform base + lane*16)
DI void cp16(const short* g, short* l) {
    __builtin_amdgcn_global_load_lds(
        (const __attribute__((address_space(1))) u32*)g,
        (__attribute__((address_space(3))) u32*)l, 16, 0, 0);
}

DI float fexp2(float x) {
#if __has_builtin(__builtin_amdgcn_exp2f)
    return __builtin_amdgcn_exp2f(x);
#else
    return exp2f(x);
#endif
}
DI float frcp(float x) {
#if __has_builtin(__builtin_amdgcn_rcpf)
    return __builtin_amdgcn_rcpf(x);
#else
    return 1.0f / x;
#endif
}

// ---- X [8192][1024] f32 -> X2 [8192][2048] bf16 : cols [0,1024)=hi, [1024,2048)=lo
__global__ void xconv_kernel(const float* __restrict__ X, short* __restrict__ X2) {
    size_t i = ((size_t)blockIdx.x * 256 + threadIdx.x) * 4;
    float4 v = *reinterpret_cast<const float4*>(X + i);
    int m = (int)(i >> 10);
    int k = (int)(i & 1023);
    float vv[4] = {v.x, v.y, v.z, v.w};
    short hi[4], lo[4];
#pragma unroll
    for (int j = 0; j < 4; ++j) { hi[j] = f2bf(vv[j]); lo[j] = f2bf(vv[j] - bf2f(hi[j])); }
    s16x4 h4 = {hi[0], hi[1], hi[2], hi[3]};
    s16x4 l4 = {lo[0], lo[1], lo[2], lo[3]};
    *reinterpret_cast<s16x4*>(X2 + (size_t)m * 2048 + k) = h4;
    *reinterpret_cast<s16x4*>(X2 + (size_t)m * 2048 + 1024 + k) = l4;
}

// ---- Wq/Wk/Wv [1024][1024] f32 -> WT2 [3072][2048] bf16 (transposed; [n][k]: hi at k, lo at 1024+k)
__global__ void wqkv_conv(const float* __restrict__ Wq, const float* __restrict__ Wk,
                          const float* __restrict__ Wv, short* __restrict__ WT2) {
    __shared__ float t[32][33];
    int z = blockIdx.z;
    const float* W = (z == 0) ? Wq : (z == 1 ? Wk : Wv);
    int k0 = blockIdx.x * 32, n0 = blockIdx.y * 32;
    int tx = threadIdx.x, ty = threadIdx.y;
#pragma unroll
    for (int i = 0; i < 4; ++i)
        t[ty + 8 * i][tx] = W[(size_t)(k0 + ty + 8 * i) * 1024 + n0 + tx];
    __syncthreads();
#pragma unroll
    for (int i = 0; i < 4; ++i) {
        float v = t[tx][ty + 8 * i];
        short hi = f2bf(v), lo = f2bf(v - bf2f(hi));
        size_t r = (size_t)(z * 1024 + n0 + ty + 8 * i) * 2048 + k0 + tx;
        WT2[r] = hi;
        WT2[r + 1024] = lo;
    }
}

// ---- Wo [1024][1024] f32 -> WoT [1024][1024] bf16 (transposed, hi only)
__global__ void wo_conv(const float* __restrict__ Wo, short* __restrict__ WoT) {
    __shared__ float t[32][33];
    int k0 = blockIdx.x * 32, n0 = blockIdx.y * 32;
    int tx = threadIdx.x, ty = threadIdx.y;
#pragma unroll
    for (int i = 0; i < 4; ++i)
        t[ty + 8 * i][tx] = Wo[(size_t)(k0 + ty + 8 * i) * 1024 + n0 + tx];
    __syncthreads();
#pragma unroll
    for (int i = 0; i < 4; ++i)
        WoT[(size_t)(n0 + ty + 8 * i) * 1024 + k0 + tx] = f2bf(t[tx][ty + 8 * i]);
}

// ---- bias table [16][4096] bf16, PRE-SCALED by log2(e): tab[h][delta+2047] = log2e*rel_bias[bucket][h]
// Exact integer thresholds equivalent to int(log(rel/8)/log(16)*8) under correctly-rounded log.
__global__ void bias_kernel(const float* __restrict__ rel_bias, short* __restrict__ tab) {
    int idx = blockIdx.x * 256 + threadIdx.x;  // 16*4096
    int h = idx >> 12;
    int i = idx & 4095;
    int delta = i - 2047;
    int ad = delta < 0 ? -delta : delta;
    int b;
    if (ad < 8) b = ad;
    else if (ad < 12) b = 8;
    else if (ad < 16) b = 9;
    else if (ad < 23) b = 10;
    else if (ad < 32) b = 11;
    else if (ad < 46) b = 12;
    else if (ad < 64) b = 13;
    else if (ad < 91) b = 14;
    else b = 15;
    if (delta > 0) b += 16;
    tab[idx] = f2bf(rel_bias[b * 16 + h] * LOG2E);
}

// ---- GEMM (proven r5 m97-structure): C[M,N] = A[M,K'] * B[K',N], B given as B^T [N][K'].
// global_load_lds staging, single LDS buffer, 2 barriers per K-step.
// Split-K' remap: colA = kk - (kk>=aWrap ? aWrap : 0), same for B.
// EPI=0: fp32 C.  EPI=1 (QK): Q'(log2e, hi|lo) and K'(hi|lo).  EPI=2 (V): V^T bf16.
template <int EPI>
__launch_bounds__(256)
__global__ void gemm_bt(const short* __restrict__ A, const short* __restrict__ Bt,
                        int K, int lda, int ldb, int aWrap, int bWrap,
                        float* __restrict__ C, int ldc,
                        short* __restrict__ q2, short* __restrict__ k2, short* __restrict__ vt) {
    __shared__ __align__(16) short As[128 * 32];
    __shared__ __align__(16) short Bs[128 * 32];
    const int tid = threadIdx.x;
    const int w = tid >> 6, l = tid & 63;
    const int m0 = blockIdx.x * 128, n0 = blockIdx.y * 128;
    const int wm = (w >> 1) * 64, wn = (w & 1) * 64;
    const int ar = tid >> 2, ac = (tid & 3) * 8;
    const int wb = w * 512;

    f32x4 acc[4][4];
#pragma unroll
    for (int i = 0; i < 4; ++i)
#pragma unroll
        for (int j = 0; j < 4; ++j) acc[i][j] = (f32x4){0.f, 0.f, 0.f, 0.f};

    const int nk = K / 32;
    for (int kt = 0; kt < nk; ++kt) {
        int kk = kt * 32;
        int ca = kk - (kk >= aWrap ? aWrap : 0);
        int cb = kk - (kk >= bWrap ? bWrap : 0);
        cp16(A + (size_t)(m0 + ar) * lda + ca + ac, As + wb);
        cp16(A + (size_t)(m0 + 64 + ar) * lda + ca + ac, As + 2048 + wb);
        cp16(Bt + (size_t)(n0 + ar) * ldb + cb + ac, Bs + wb);
        cp16(Bt + (size_t)(n0 + 64 + ar) * ldb + cb + ac, Bs + 2048 + wb);
        __syncthreads();
        s16x8 af[4], bfv[4];
#pragma unroll
        for (int i = 0; i < 4; ++i)
            af[i] = *reinterpret_cast<const s16x8*>(As + (wm + i * 16 + (l & 15)) * 32 + (l >> 4) * 8);
#pragma unroll
        for (int i = 0; i < 4; ++i)
            bfv[i] = *reinterpret_cast<const s16x8*>(Bs + (wn + i * 16 + (l & 15)) * 32 + (l >> 4) * 8);
#pragma unroll
        for (int mi = 0; mi < 4; ++mi)
#pragma unroll
            for (int ni = 0; ni < 4; ++ni)
                acc[mi][ni] = __builtin_amdgcn_mfma_f32_16x16x32_bf16(af[mi], bfv[ni], acc[mi][ni], 0, 0, 0);
        __syncthreads();
    }

    const int rl = l >> 4, cl = l & 15;
    if (EPI == 0) {
#pragma unroll
        for (int mi = 0; mi < 4; ++mi) {
            int row = m0 + wm + mi * 16 + rl * 4;
#pragma unroll
            for (int ni = 0; ni < 4; ++ni) {
                int col = n0 + wn + ni * 16 + cl;
#pragma unroll
                for (int r = 0; r < 4; ++r)
                    C[(size_t)(row + r) * ldc + col] = acc[mi][ni][r];
            }
        }
    } else if (EPI == 1) {
        int region = n0 >> 10;  // block-uniform: 0=Q 1=K
#pragma unroll
        for (int mi = 0; mi < 4; ++mi) {
#pragma unroll
            for (int ni = 0; ni < 4; ++ni) {
#pragma unroll
                for (int r = 0; r < 4; ++r) {
                    int m = m0 + wm + mi * 16 + rl * 4 + r;
                    int n = (n0 & 1023) + wn + ni * 16 + cl;
                    int bb = m >> 11, s = m & 2047;
                    int h = n >> 6, d = n & 63;
                    int bh = bb * 16 + h;
                    float c = acc[mi][ni][r];
                    if (region == 0) {
                        c *= LOG2E;  // fold softmax base-2 conversion into Q
                        short hi = f2bf(c);
                        short lo = f2bf(c - bf2f(hi));
                        size_t base = ((size_t)bh * 2048 + s) * 128;
                        q2[base + d] = hi;
                        q2[base + 64 + d] = lo;
                    } else {
                        short hi = f2bf(c);
                        short lo = f2bf(c - bf2f(hi));
                        size_t base = ((size_t)bh * 2048 + s) * 128;
                        k2[base + d] = hi;
                        k2[base + 64 + d] = lo;
                    }
                }
            }
        }
    } else {  // EPI == 2: V^T epilogue (single-bf16 V projection)
#pragma unroll
        for (int mi = 0; mi < 4; ++mi) {
#pragma unroll
            for (int ni = 0; ni < 4; ++ni) {
#pragma unroll
                for (int r = 0; r < 4; ++r) {
                    int m = m0 + wm + mi * 16 + rl * 4 + r;
                    int n = n0 + wn + ni * 16 + cl;  // n in [0,1024)
                    int bb = m >> 11, s = m & 2047;
                    int h = n >> 6, d = n & 63;
                    int bh = bb * 16 + h;
                    vt[((size_t)bh * 64 + d) * 2048 + s] = f2bf(acc[mi][ni][r]);
                }
            }
        }
    }
}

// ---- Flash attention, 32x32 swapped-operand form (structure validated r5/r8).
// Grid: 512 blocks (XCD-swizzled), 512 threads = 8 waves; wave owns 32 q-rows (q-block 256).
// Swapped QK: mfma(A=K', B=Q') -> lane holds 16 scores of ONE q-row (q = lane&31).
// P stays in registers; cross-half exchange via v_permlane32_swap_b32 (VALU).
// Bias pairs read as ONE aligned ds_read_b32 via dual-parity tables Bsh0/Bsh1.
// Index bound (r9 NaN post-mortem): i0 = kvg - qL + 255, kvg<=2046, qL>=0 -> i0<=2301;
// Bsh0 needs i0+1 <= 2302 (size 2304, fill 2304); Bsh1 needs index i0 <= 2301 (fill 2302).
// No online max (|score*log2e| < ~90 << 127, exp2/fp32-sum safe); psum is in-lane scalar.
__launch_bounds__(512, 4)
__global__ void flash_kernel(const short* __restrict__ q2, const short* __restrict__ k2,
                             const short* __restrict__ vt, const short* __restrict__ btab,
                             short* __restrict__ attnb) {
    __shared__ __align__(16) short Ks[2][8192];   // [buf] 64 rows x 16 chunks(16B), slot = c ^ (r&15)
    __shared__ __align__(16) short Vs[2][4096];   // [buf] 64 d-rows x 8 chunks, slot = c ^ (d&7)
    __shared__ __align__(16) short Bsh0[2304];    // bias slice (bf16, log2e-scaled)
    __shared__ __align__(16) short Bsh1[2304];    // same shifted by +1 (odd-parity pair reads)

    const int tid = threadIdx.x;
    const int w = tid >> 6, l = tid & 63;
    const int l31 = l & 31, hi = l >> 5;

    const int L = blockIdx.x;
    const int xcd = L & 7, idx = L >> 3;
    const int bh = xcd + 8 * (idx & 7);
    const int qb = idx >> 3;
    const int h = bh & 15;
    const int q0b = qb * 256;
    const int qw0 = q0b + w * 32;
    const int qL = w * 32 + l31;

    const short* Q = q2 + (size_t)bh * Sc * 128;
    const short* Kp = k2 + (size_t)bh * Sc * 128;
    const short* V = vt + (size_t)bh * 64 * Sc;

    {
        int base = h * 4096 + 1792 - q0b;
        for (int i = tid; i < 2304; i += 512) Bsh0[i] = btab[base + i];
        // Need Bsh1[j] for j <= i0 <= 2301 -> fill j < 2302 (btab idx <= base+2302 <= h*4096+4094, in-bounds)
        for (int i = tid; i < 2302; i += 512) Bsh1[i] = btab[base + i + 1];
    }

    auto stage = [&](int buf, int it2) {
        int kv0 = it2 * 64;
#pragma unroll
        for (int j = 0; j < 2; ++j) {
            int o = w * 128 + j * 64 + l;
            int r = o >> 4, cs = o & 15;
            int cg = cs ^ (r & 15);
            cp16(Kp + (size_t)(kv0 + r) * 128 + cg * 8, &Ks[buf][(w * 128 + j * 64) * 8]);
        }
        {
            int o = w * 64 + l;
            int d = o >> 3, cs = o & 7;
            int cg = cs ^ (d & 7);
            cp16(V + (size_t)d * 2048 + kv0 + cg * 8, &Vs[buf][(w * 64) * 8]);
        }
    };

    s16x8 qf[8];
#pragma unroll
    for (int c = 0; c < 8; ++c)
        qf[c] = *reinterpret_cast<const s16x8*>(Q + (size_t)(qw0 + l31) * 128 + c * 16 + hi * 8);

    f32x16 accO[2];
#pragma unroll
    for (int i = 0; i < 16; ++i) { accO[0][i] = 0.f; accO[1][i] = 0.f; }
    float psum = 0.f;

    stage(0, 0);
    __syncthreads();

    for (int it = 0; it < 32; ++it) {
        const int cur = it & 1;
        if (it + 1 < 32) stage(cur ^ 1, it + 1);
        const int kv0 = it * 64;
#pragma unroll
        for (int T = 0; T < 2; ++T) {
            const int rA = T * 32 + l31;
            const int rsw = rA & 15;
            const short* kbase = &Ks[cur][rA * 128];
            s16x8 kh[4];
#pragma unroll
            for (int c = 0; c < 4; ++c)
                kh[c] = *reinterpret_cast<const s16x8*>(kbase + ((c * 2 + hi) ^ rsw) * 8);
            f32x16 acc = {0.f,0.f,0.f,0.f,0.f,0.f,0.f,0.f,0.f,0.f,0.f,0.f,0.f,0.f,0.f,0.f};
#pragma unroll
            for (int c = 0; c < 4; ++c)
                acc = __builtin_amdgcn_mfma_f32_32x32x16_bf16(kh[c], qf[c], acc, 0, 0, 0);
#pragma unroll
            for (int c = 0; c < 4; ++c)
                acc = __builtin_amdgcn_mfma_f32_32x32x16_bf16(kh[c], qf[c + 4], acc, 0, 0, 0);
#pragma unroll
            for (int c = 0; c < 4; ++c) {
                s16x8 klo = *reinterpret_cast<const s16x8*>(kbase + (((c + 4) * 2 + hi) ^ rsw) * 8);
                acc = __builtin_amdgcn_mfma_f32_32x32x16_bf16(klo, qf[c], acc, 0, 0, 0);
            }
#pragma unroll
            for (int t2 = 0; t2 < 2; ++t2) {
                u32 pk[4];
#pragma unroll
                for (int i = 0; i < 4; ++i) {
                    const int ii = t2 * 4 + i;
                    const int pstart = ((ii & 1) * 2) + ((ii >> 1) * 8);
                    const int kvg = kv0 + T * 32 + pstart + 4 * hi;  // even
                    const int i0 = kvg - qL + 255;                   // parity = parity(qL+1)
                    const short* bp = (i0 & 1) ? (Bsh1 + (i0 - 1)) : (Bsh0 + i0);
                    const u32 pr2 = *reinterpret_cast<const u32*>(bp);  // 4B-aligned
                    const float b0 = bf2f((short)(pr2 & 0xffff));
                    const float b1 = bf2f((short)(pr2 >> 16));
                    const int r0 = t2 * 8 + i * 2;
                    const float e0 = fexp2(acc[r0] + b0);
                    const float e1 = fexp2(acc[r0 + 1] + b1);
                    psum += e0 + e1;
                    pk[i] = pack2(e0, e1);
                }
                // cross-half exchange in-register:
                // after swap(pk0,pk2): pk0 = [pk0.row0, pk2.row0] (= d0), pk2 = [pk0.row1, pk2.row1] (= d2)
                pl32swap(pk[0], pk[2]);
                pl32swap(pk[1], pk[3]);
                u32x4 pv4 = {pk[0], pk[1], pk[2], pk[3]};
                s16x8 pfrag = __builtin_bit_cast(s16x8, pv4);
                const int tg = T * 2 + t2;
#pragma unroll
                for (int dt = 0; dt < 2; ++dt) {
                    const int d = dt * 32 + l31;
                    s16x8 vf = *reinterpret_cast<const s16x8*>(
                        &Vs[cur][d * 64 + ((tg * 2 + hi) ^ (d & 7)) * 8]);
                    accO[dt] = __builtin_amdgcn_mfma_f32_32x32x16_bf16(pfrag, vf, accO[dt], 0, 0, 0);
                }
            }
        }
        __syncthreads();
    }

    psum += __shfl_xor(psum, 32);

    const int bb = bh >> 4;
#pragma unroll
    for (int r = 0; r < 16; ++r) {
        const int qloc = (r & 3) + 8 * (r >> 2) + 4 * hi;
        const float inv = frcp(__shfl(psum, qloc));
        const size_t rowbase = ((size_t)(bb * 2048 + qw0 + qloc)) * 1024 + h * 64;
#pragma unroll
        for (int dt = 0; dt < 2; ++dt)
            attnb[rowbase + dt * 32 + l31] = f2bf(accO[dt][r] * inv);
    }
}

extern "C" void kernel_launch(void* const* d_in, const int* in_sizes, int n_in,
                              void* d_out, int out_size, void* d_ws, size_t ws_size,
                              hipStream_t stream) {
    const float* X = (const float*)d_in[0];
    const float* Wq = (const float*)d_in[1];
    const float* Wk = (const float*)d_in[2];
    const float* Wv = (const float*)d_in[3];
    const float* Wo = (const float*)d_in[4];
    const float* RB = (const float*)d_in[5];

    char* ws = (char*)d_ws;
    size_t off = 0;
    auto alloc = [&](size_t bytes) {
        void* p = ws + off;
        off += (bytes + 255) & ~(size_t)255;
        return p;
    };
    short* X2 = (short*)alloc((size_t)8192 * 2048 * 2);
    short* WT2 = (short*)alloc((size_t)3072 * 2048 * 2);
    short* q2 = (short*)alloc((size_t)64 * 2048 * 128 * 2);
    short* k2 = (short*)alloc((size_t)64 * 2048 * 128 * 2);
    short* vt = (short*)alloc((size_t)64 * 64 * 2048 * 2);
    short* attn = (short*)alloc((size_t)8192 * 1024 * 2);
    short* WoT = (short*)alloc((size_t)1024 * 1024 * 2);
    short* btab = (short*)alloc((size_t)16 * 4096 * 2);

    xconv_kernel<<<8192, 256, 0, stream>>>(X, X2);
    wqkv_conv<<<dim3(32, 32, 3), dim3(32, 8), 0, stream>>>(Wq, Wk, Wv, WT2);
    wo_conv<<<dim3(32, 32), dim3(32, 8), 0, stream>>>(Wo, WoT);
    bias_kernel<<<256, 256, 0, stream>>>(RB, btab);
    // QK projection (3-term split, K'=3072): A=[Xhi|Xhi|Xlo] via aWrap, B=[Whi|Wlo|Whi] via bWrap
    gemm_bt<1><<<dim3(64, 16), 256, 0, stream>>>(X2, WT2, 3072, 2048, 2048, 1024, 2048,
                                                 nullptr, 0, q2, k2, nullptr);
    // V projection (single bf16, K=1024): A=Xhi, B=Wv^T hi rows (WT2 rows 2048..3071)
    gemm_bt<2><<<dim3(64, 8), 256, 0, stream>>>(X2, WT2 + (size_t)2048 * 2048, 1024, 2048, 2048,
                                                1 << 30, 1 << 30, nullptr, 0, nullptr, nullptr, vt);
    flash_kernel<<<512, 512, 0, stream>>>(q2, k2, vt, btab, attn);
    // Output projection (single bf16)
    gemm_bt<0><<<dim3(64, 8), 256, 0, stream>>>(attn, WoT, 1024, 1024, 1024, 1 << 30, 1 << 30,
                                                (float*)d_out, 1024, nullptr, nullptr, nullptr);
}

// Round 11
// 384.694 us; speedup vs baseline: 1.5055x; 1.0461x over previous
//
#include <hip/hip_runtime.h>
#include <hip/hip_bf16.h>
#include <cstdint>

#define DI __device__ __forceinline__

typedef __attribute__((ext_vector_type(4))) float f32x4;
typedef __attribute__((ext_vector_type(16))) float f32x16;
typedef __attribute__((ext_vector_type(8))) short s16x8;
typedef __attribute__((ext_vector_type(4))) short s16x4;
typedef __attribute__((ext_vector_type(4))) unsigned int u32x4;
typedef unsigned int u32;

constexpr int Sc = 2048;
constexpr float LOG2E = 1.44269504088896340736f;
// B=4, D=1024, H=16, DK=64, M = B*S = 8192, BH = 64

DI short f2bf(float x) {
    __hip_bfloat16 h = __float2bfloat16(x);
    return __builtin_bit_cast(short, h);
}
DI float bf2f(short x) {
    __hip_bfloat16 h = __builtin_bit_cast(__hip_bfloat16, x);
    return __bfloat162float(h);
}
// pack two f32 -> dword of 2 bf16 (lo = a, hi = b) via verified scalar converts
DI u32 pack2(float a, float b) {
    return (u32)(unsigned short)f2bf(a) | ((u32)(unsigned short)f2bf(b) << 16);
}
// swap rows: a' = [a.row0, b.row0]; b' = [a.row1, b.row1]  (rows = 32-lane halves)
DI void pl32swap(u32& a, u32& b) {
    asm("v_permlane32_swap_b32 %0, %1" : "+v"(a), "+v"(b));
}

// async 16B global -> LDS (dest = wave-uniform base + lane*16)
DI void cp16(const short* g, short* l) {
    __builtin_amdgcn_global_load_lds(
        (const __attribute__((address_space(1))) u32*)g,
        (__attribute__((address_space(3))) u32*)l, 16, 0, 0);
}

DI float fexp2(float x) {
#if __has_builtin(__builtin_amdgcn_exp2f)
    return __builtin_amdgcn_exp2f(x);
#else
    return exp2f(x);
#endif
}
DI float frcp(float x) {
#if __has_builtin(__builtin_amdgcn_rcpf)
    return __builtin_amdgcn_rcpf(x);
#else
    return 1.0f / x;
#endif
}

// ---- X [8192][1024] f32 -> X2 [8192][2048] bf16 : cols [0,1024)=hi, [1024,2048)=lo
__global__ void xconv_kernel(const float* __restrict__ X, short* __restrict__ X2) {
    size_t i = ((size_t)blockIdx.x * 256 + threadIdx.x) * 4;
    float4 v = *reinterpret_cast<const float4*>(X + i);
    int m = (int)(i >> 10);
    int k = (int)(i & 1023);
    float vv[4] = {v.x, v.y, v.z, v.w};
    short hi[4], lo[4];
#pragma unroll
    for (int j = 0; j < 4; ++j) { hi[j] = f2bf(vv[j]); lo[j] = f2bf(vv[j] - bf2f(hi[j])); }
    s16x4 h4 = {hi[0], hi[1], hi[2], hi[3]};
    s16x4 l4 = {lo[0], lo[1], lo[2], lo[3]};
    *reinterpret_cast<s16x4*>(X2 + (size_t)m * 2048 + k) = h4;
    *reinterpret_cast<s16x4*>(X2 + (size_t)m * 2048 + 1024 + k) = l4;
}

// ---- Wq/Wk/Wv [1024][1024] f32 -> WT2 [3072][2048] bf16 (transposed; [n][k]: hi at k, lo at 1024+k)
__global__ void wqkv_conv(const float* __restrict__ Wq, const float* __restrict__ Wk,
                          const float* __restrict__ Wv, short* __restrict__ WT2) {
    __shared__ float t[32][33];
    int z = blockIdx.z;
    const float* W = (z == 0) ? Wq : (z == 1 ? Wk : Wv);
    int k0 = blockIdx.x * 32, n0 = blockIdx.y * 32;
    int tx = threadIdx.x, ty = threadIdx.y;
#pragma unroll
    for (int i = 0; i < 4; ++i)
        t[ty + 8 * i][tx] = W[(size_t)(k0 + ty + 8 * i) * 1024 + n0 + tx];
    __syncthreads();
#pragma unroll
    for (int i = 0; i < 4; ++i) {
        float v = t[tx][ty + 8 * i];
        short hi = f2bf(v), lo = f2bf(v - bf2f(hi));
        size_t r = (size_t)(z * 1024 + n0 + ty + 8 * i) * 2048 + k0 + tx;
        WT2[r] = hi;
        WT2[r + 1024] = lo;
    }
}

// ---- Wo [1024][1024] f32 -> WoT [1024][1024] bf16 (transposed, hi only)
__global__ void wo_conv(const float* __restrict__ Wo, short* __restrict__ WoT) {
    __shared__ float t[32][33];
    int k0 = blockIdx.x * 32, n0 = blockIdx.y * 32;
    int tx = threadIdx.x, ty = threadIdx.y;
#pragma unroll
    for (int i = 0; i < 4; ++i)
        t[ty + 8 * i][tx] = Wo[(size_t)(k0 + ty + 8 * i) * 1024 + n0 + tx];
    __syncthreads();
#pragma unroll
    for (int i = 0; i < 4; ++i)
        WoT[(size_t)(n0 + ty + 8 * i) * 1024 + k0 + tx] = f2bf(t[tx][ty + 8 * i]);
}

// ---- bias table [16][4096] bf16, PRE-SCALED by log2(e): tab[h][delta+2047] = log2e*rel_bias[bucket][h]
// Exact integer thresholds equivalent to int(log(rel/8)/log(16)*8) under correctly-rounded log.
__global__ void bias_kernel(const float* __restrict__ rel_bias, short* __restrict__ tab) {
    int idx = blockIdx.x * 256 + threadIdx.x;  // 16*4096
    int h = idx >> 12;
    int i = idx & 4095;
    int delta = i - 2047;
    int ad = delta < 0 ? -delta : delta;
    int b;
    if (ad < 8) b = ad;
    else if (ad < 12) b = 8;
    else if (ad < 16) b = 9;
    else if (ad < 23) b = 10;
    else if (ad < 32) b = 11;
    else if (ad < 46) b = 12;
    else if (ad < 64) b = 13;
    else if (ad < 91) b = 14;
    else b = 15;
    if (delta > 0) b += 16;
    tab[idx] = f2bf(rel_bias[b * 16 + h] * LOG2E);
}

// ---- GEMM (proven r5 m97-structure): C[M,N] = A[M,K'] * B[K',N], B given as B^T [N][K'].
// global_load_lds staging, single LDS buffer, 2 barriers per K-step.
// Split-K' remap: colA = kk - (kk>=aWrap ? aWrap : 0), same for B.
// EPI=0: fp32 C.
// EPI=1 (fused QKV, r11): region = n0>>10 (block-uniform). Q/K regions run full K'=3072
// (3-term hi/lo split); V region EARLY-EXITS at kt=32 (kk<1024 -> A=Xhi, B=Wv-hi only,
// bit-identical to the r10 separate V dispatch) and stores V^T bf16. One big dispatch
// (1536 blocks = 6/CU) restores the TLP the r7 split lost.
template <int EPI>
__launch_bounds__(256)
__global__ void gemm_bt(const short* __restrict__ A, const short* __restrict__ Bt,
                        int K, int lda, int ldb, int aWrap, int bWrap,
                        float* __restrict__ C, int ldc,
                        short* __restrict__ q2, short* __restrict__ k2, short* __restrict__ vt) {
    __shared__ __align__(16) short As[128 * 32];
    __shared__ __align__(16) short Bs[128 * 32];
    const int tid = threadIdx.x;
    const int w = tid >> 6, l = tid & 63;
    const int m0 = blockIdx.x * 128, n0 = blockIdx.y * 128;
    const int wm = (w >> 1) * 64, wn = (w & 1) * 64;
    const int ar = tid >> 2, ac = (tid & 3) * 8;
    const int wb = w * 512;

    const int region = (EPI == 1) ? (n0 >> 10) : 0;  // 0=Q 1=K 2=V (block-uniform)

    f32x4 acc[4][4];
#pragma unroll
    for (int i = 0; i < 4; ++i)
#pragma unroll
        for (int j = 0; j < 4; ++j) acc[i][j] = (f32x4){0.f, 0.f, 0.f, 0.f};

    const int nk = K / 32;
    const int nkUse = (EPI == 1 && region == 2) ? 32 : nk;  // V: hh-term only
    for (int kt = 0; kt < nkUse; ++kt) {
        int kk = kt * 32;
        int ca = kk - (kk >= aWrap ? aWrap : 0);
        int cb = kk - (kk >= bWrap ? bWrap : 0);
        cp16(A + (size_t)(m0 + ar) * lda + ca + ac, As + wb);
        cp16(A + (size_t)(m0 + 64 + ar) * lda + ca + ac, As + 2048 + wb);
        cp16(Bt + (size_t)(n0 + ar) * ldb + cb + ac, Bs + wb);
        cp16(Bt + (size_t)(n0 + 64 + ar) * ldb + cb + ac, Bs + 2048 + wb);
        __syncthreads();
        s16x8 af[4], bfv[4];
#pragma unroll
        for (int i = 0; i < 4; ++i)
            af[i] = *reinterpret_cast<const s16x8*>(As + (wm + i * 16 + (l & 15)) * 32 + (l >> 4) * 8);
#pragma unroll
        for (int i = 0; i < 4; ++i)
            bfv[i] = *reinterpret_cast<const s16x8*>(Bs + (wn + i * 16 + (l & 15)) * 32 + (l >> 4) * 8);
#pragma unroll
        for (int mi = 0; mi < 4; ++mi)
#pragma unroll
            for (int ni = 0; ni < 4; ++ni)
                acc[mi][ni] = __builtin_amdgcn_mfma_f32_16x16x32_bf16(af[mi], bfv[ni], acc[mi][ni], 0, 0, 0);
        __syncthreads();
    }

    const int rl = l >> 4, cl = l & 15;
    if (EPI == 0) {
#pragma unroll
        for (int mi = 0; mi < 4; ++mi) {
            int row = m0 + wm + mi * 16 + rl * 4;
#pragma unroll
            for (int ni = 0; ni < 4; ++ni) {
                int col = n0 + wn + ni * 16 + cl;
#pragma unroll
                for (int r = 0; r < 4; ++r)
                    C[(size_t)(row + r) * ldc + col] = acc[mi][ni][r];
            }
        }
    } else {
#pragma unroll
        for (int mi = 0; mi < 4; ++mi) {
#pragma unroll
            for (int ni = 0; ni < 4; ++ni) {
#pragma unroll
                for (int r = 0; r < 4; ++r) {
                    int m = m0 + wm + mi * 16 + rl * 4 + r;
                    int n = (n0 & 1023) + wn + ni * 16 + cl;
                    int bb = m >> 11, s = m & 2047;
                    int h = n >> 6, d = n & 63;
                    int bh = bb * 16 + h;
                    float c = acc[mi][ni][r];
                    if (region == 0) {
                        c *= LOG2E;  // fold softmax base-2 conversion into Q
                        short hi = f2bf(c);
                        short lo = f2bf(c - bf2f(hi));
                        size_t base = ((size_t)bh * 2048 + s) * 128;
                        q2[base + d] = hi;
                        q2[base + 64 + d] = lo;
                    } else if (region == 1) {
                        short hi = f2bf(c);
                        short lo = f2bf(c - bf2f(hi));
                        size_t base = ((size_t)bh * 2048 + s) * 128;
                        k2[base + d] = hi;
                        k2[base + 64 + d] = lo;
                    } else {
                        vt[((size_t)bh * 64 + d) * 2048 + s] = f2bf(c);
                    }
                }
            }
        }
    }
}

// ---- Flash attention, 32x32 swapped-operand form (validated r5/r8/r10).
// Grid: 512 blocks (XCD-swizzled), 512 threads = 8 waves; wave owns 32 q-rows (q-block 256).
// Swapped QK: mfma(A=K', B=Q') -> lane holds 16 scores of ONE q-row (q = lane&31).
// P stays in registers; cross-half exchange via v_permlane32_swap_b32 (VALU).
// Bias pairs read as ONE aligned ds_read_b32 via dual-parity tables Bsh0/Bsh1.
// Index bound: i0 = kvg - qL + 255 <= 2301; Bsh0 fill 2304, Bsh1 fill 2302.
// No online max (|score*log2e| < ~90 << 127, exp2/fp32-sum safe); psum is in-lane scalar.
__launch_bounds__(512, 4)
__global__ void flash_kernel(const short* __restrict__ q2, const short* __restrict__ k2,
                             const short* __restrict__ vt, const short* __restrict__ btab,
                             short* __restrict__ attnb) {
    __shared__ __align__(16) short Ks[2][8192];   // [buf] 64 rows x 16 chunks(16B), slot = c ^ (r&15)
    __shared__ __align__(16) short Vs[2][4096];   // [buf] 64 d-rows x 8 chunks, slot = c ^ (d&7)
    __shared__ __align__(16) short Bsh0[2304];    // bias slice (bf16, log2e-scaled)
    __shared__ __align__(16) short Bsh1[2304];    // same shifted by +1 (odd-parity pair reads)

    const int tid = threadIdx.x;
    const int w = tid >> 6, l = tid & 63;
    const int l31 = l & 31, hi = l >> 5;

    const int L = blockIdx.x;
    const int xcd = L & 7, idx = L >> 3;
    const int bh = xcd + 8 * (idx & 7);
    const int qb = idx >> 3;
    const int h = bh & 15;
    const int q0b = qb * 256;
    const int qw0 = q0b + w * 32;
    const int qL = w * 32 + l31;

    const short* Q = q2 + (size_t)bh * Sc * 128;
    const short* Kp = k2 + (size_t)bh * Sc * 128;
    const short* V = vt + (size_t)bh * 64 * Sc;

    {
        int base = h * 4096 + 1792 - q0b;
        for (int i = tid; i < 2304; i += 512) Bsh0[i] = btab[base + i];
        for (int i = tid; i < 2302; i += 512) Bsh1[i] = btab[base + i + 1];
    }

    auto stage = [&](int buf, int it2) {
        int kv0 = it2 * 64;
#pragma unroll
        for (int j = 0; j < 2; ++j) {
            int o = w * 128 + j * 64 + l;
            int r = o >> 4, cs = o & 15;
            int cg = cs ^ (r & 15);
            cp16(Kp + (size_t)(kv0 + r) * 128 + cg * 8, &Ks[buf][(w * 128 + j * 64) * 8]);
        }
        {
            int o = w * 64 + l;
            int d = o >> 3, cs = o & 7;
            int cg = cs ^ (d & 7);
            cp16(V + (size_t)d * 2048 + kv0 + cg * 8, &Vs[buf][(w * 64) * 8]);
        }
    };

    s16x8 qf[8];
#pragma unroll
    for (int c = 0; c < 8; ++c)
        qf[c] = *reinterpret_cast<const s16x8*>(Q + (size_t)(qw0 + l31) * 128 + c * 16 + hi * 8);

    f32x16 accO[2];
#pragma unroll
    for (int i = 0; i < 16; ++i) { accO[0][i] = 0.f; accO[1][i] = 0.f; }
    float psum = 0.f;

    stage(0, 0);
    __syncthreads();

    for (int it = 0; it < 32; ++it) {
        const int cur = it & 1;
        if (it + 1 < 32) stage(cur ^ 1, it + 1);
        const int kv0 = it * 64;
#pragma unroll
        for (int T = 0; T < 2; ++T) {
            const int rA = T * 32 + l31;
            const int rsw = rA & 15;
            const short* kbase = &Ks[cur][rA * 128];
            s16x8 kh[4];
#pragma unroll
            for (int c = 0; c < 4; ++c)
                kh[c] = *reinterpret_cast<const s16x8*>(kbase + ((c * 2 + hi) ^ rsw) * 8);
            f32x16 acc = {0.f,0.f,0.f,0.f,0.f,0.f,0.f,0.f,0.f,0.f,0.f,0.f,0.f,0.f,0.f,0.f};
#pragma unroll
            for (int c = 0; c < 4; ++c)
                acc = __builtin_amdgcn_mfma_f32_32x32x16_bf16(kh[c], qf[c], acc, 0, 0, 0);
#pragma unroll
            for (int c = 0; c < 4; ++c)
                acc = __builtin_amdgcn_mfma_f32_32x32x16_bf16(kh[c], qf[c + 4], acc, 0, 0, 0);
#pragma unroll
            for (int c = 0; c < 4; ++c) {
                s16x8 klo = *reinterpret_cast<const s16x8*>(kbase + (((c + 4) * 2 + hi) ^ rsw) * 8);
                acc = __builtin_amdgcn_mfma_f32_32x32x16_bf16(klo, qf[c], acc, 0, 0, 0);
            }
#pragma unroll
            for (int t2 = 0; t2 < 2; ++t2) {
                u32 pk[4];
#pragma unroll
                for (int i = 0; i < 4; ++i) {
                    const int ii = t2 * 4 + i;
                    const int pstart = ((ii & 1) * 2) + ((ii >> 1) * 8);
                    const int kvg = kv0 + T * 32 + pstart + 4 * hi;  // even
                    const int i0 = kvg - qL + 255;
                    const short* bp = (i0 & 1) ? (Bsh1 + (i0 - 1)) : (Bsh0 + i0);
                    const u32 pr2 = *reinterpret_cast<const u32*>(bp);  // 4B-aligned
                    const float b0 = bf2f((short)(pr2 & 0xffff));
                    const float b1 = bf2f((short)(pr2 >> 16));
                    const int r0 = t2 * 8 + i * 2;
                    const float e0 = fexp2(acc[r0] + b0);
                    const float e1 = fexp2(acc[r0 + 1] + b1);
                    psum += e0 + e1;
                    pk[i] = pack2(e0, e1);
                }
                pl32swap(pk[0], pk[2]);
                pl32swap(pk[1], pk[3]);
                u32x4 pv4 = {pk[0], pk[1], pk[2], pk[3]};
                s16x8 pfrag = __builtin_bit_cast(s16x8, pv4);
                const int tg = T * 2 + t2;
#pragma unroll
                for (int dt = 0; dt < 2; ++dt) {
                    const int d = dt * 32 + l31;
                    s16x8 vf = *reinterpret_cast<const s16x8*>(
                        &Vs[cur][d * 64 + ((tg * 2 + hi) ^ (d & 7)) * 8]);
                    accO[dt] = __builtin_amdgcn_mfma_f32_32x32x16_bf16(pfrag, vf, accO[dt], 0, 0, 0);
                }
            }
        }
        __syncthreads();
    }

    psum += __shfl_xor(psum, 32);

    const int bb = bh >> 4;
#pragma unroll
    for (int r = 0; r < 16; ++r) {
        const int qloc = (r & 3) + 8 * (r >> 2) + 4 * hi;
        const float inv = frcp(__shfl(psum, qloc));
        const size_t rowbase = ((size_t)(bb * 2048 + qw0 + qloc)) * 1024 + h * 64;
#pragma unroll
        for (int dt = 0; dt < 2; ++dt)
            attnb[rowbase + dt * 32 + l31] = f2bf(accO[dt][r] * inv);
    }
}

extern "C" void kernel_launch(void* const* d_in, const int* in_sizes, int n_in,
                              void* d_out, int out_size, void* d_ws, size_t ws_size,
                              hipStream_t stream) {
    const float* X = (const float*)d_in[0];
    const float* Wq = (const float*)d_in[1];
    const float* Wk = (const float*)d_in[2];
    const float* Wv = (const float*)d_in[3];
    const float* Wo = (const float*)d_in[4];
    const float* RB = (const float*)d_in[5];

    char* ws = (char*)d_ws;
    size_t off = 0;
    auto alloc = [&](size_t bytes) {
        void* p = ws + off;
        off += (bytes + 255) & ~(size_t)255;
        return p;
    };
    short* X2 = (short*)alloc((size_t)8192 * 2048 * 2);
    short* WT2 = (short*)alloc((size_t)3072 * 2048 * 2);
    short* q2 = (short*)alloc((size_t)64 * 2048 * 128 * 2);
    short* k2 = (short*)alloc((size_t)64 * 2048 * 128 * 2);
    short* vt = (short*)alloc((size_t)64 * 64 * 2048 * 2);
    short* attn = (short*)alloc((size_t)8192 * 1024 * 2);
    short* WoT = (short*)alloc((size_t)1024 * 1024 * 2);
    short* btab = (short*)alloc((size_t)16 * 4096 * 2);

    xconv_kernel<<<8192, 256, 0, stream>>>(X, X2);
    wqkv_conv<<<dim3(32, 32, 3), dim3(32, 8), 0, stream>>>(Wq, Wk, Wv, WT2);
    wo_conv<<<dim3(32, 32), dim3(32, 8), 0, stream>>>(Wo, WoT);
    bias_kernel<<<256, 256, 0, stream>>>(RB, btab);
    // Fused QKV projection, one dispatch (1536 blocks): Q/K regions full 3-term K'=3072,
    // V region early-exits at kk=1024 (hh only). A=[Xhi|Xhi|Xlo] via aWrap, B=[Whi|Wlo|Whi] via bWrap.
    gemm_bt<1><<<dim3(64, 24), 256, 0, stream>>>(X2, WT2, 3072, 2048, 2048, 1024, 2048,
                                                 nullptr, 0, q2, k2, vt);
    flash_kernel<<<512, 512, 0, stream>>>(q2, k2, vt, btab, attn);
    // Output projection (single bf16)
    gemm_bt<0><<<dim3(64, 8), 256, 0, stream>>>(attn, WoT, 1024, 1024, 1024, 1 << 30, 1 << 30,
                                                (float*)d_out, 1024, nullptr, nullptr, nullptr);
}

// Round 12
// 304.378 us; speedup vs baseline: 1.9027x; 1.2639x over previous
//
#include <hip/hip_runtime.h>
#include <hip/hip_bf16.h>
#include <cstdint>

#define DI __device__ __forceinline__

typedef __attribute__((ext_vector_type(4))) float f32x4;
typedef __attribute__((ext_vector_type(16))) float f32x16;
typedef __attribute__((ext_vector_type(8))) short s16x8;
typedef __attribute__((ext_vector_type(4))) short s16x4;
typedef __attribute__((ext_vector_type(4))) unsigned int u32x4;
typedef unsigned int u32;

constexpr int Sc = 2048;
constexpr float LOG2E = 1.44269504088896340736f;
// B=4, D=1024, H=16, DK=64, M = B*S = 8192, BH = 64

DI short f2bf(float x) {
    __hip_bfloat16 h = __float2bfloat16(x);
    return __builtin_bit_cast(short, h);
}
DI float bf2f(short x) {
    __hip_bfloat16 h = __builtin_bit_cast(__hip_bfloat16, x);
    return __bfloat162float(h);
}
// pack two f32 -> dword of 2 bf16 (lo = a, hi = b) via verified scalar converts
DI u32 pack2(float a, float b) {
    return (u32)(unsigned short)f2bf(a) | ((u32)(unsigned short)f2bf(b) << 16);
}
// swap rows: a' = [a.row0, b.row0]; b' = [a.row1, b.row1]  (rows = 32-lane halves)
DI void pl32swap(u32& a, u32& b) {
    asm("v_permlane32_swap_b32 %0, %1" : "+v"(a), "+v"(b));
}

// async 16B global -> LDS (dest = wave-uniform base + lane*16)
DI void cp16(const short* g, short* l) {
    __builtin_amdgcn_global_load_lds(
        (const __attribute__((address_space(1))) u32*)g,
        (__attribute__((address_space(3))) u32*)l, 16, 0, 0);
}

DI float fexp2(float x) {
#if __has_builtin(__builtin_amdgcn_exp2f)
    return __builtin_amdgcn_exp2f(x);
#else
    return exp2f(x);
#endif
}
DI float frcp(float x) {
#if __has_builtin(__builtin_amdgcn_rcpf)
    return __builtin_amdgcn_rcpf(x);
#else
    return 1.0f / x;
#endif
}

// ---- X [8192][1024] f32 -> X2 [8192][2048] bf16 : cols [0,1024)=hi, [1024,2048)=lo
__global__ void xconv_kernel(const float* __restrict__ X, short* __restrict__ X2) {
    size_t i = ((size_t)blockIdx.x * 256 + threadIdx.x) * 4;
    float4 v = *reinterpret_cast<const float4*>(X + i);
    int m = (int)(i >> 10);
    int k = (int)(i & 1023);
    float vv[4] = {v.x, v.y, v.z, v.w};
    short hi[4], lo[4];
#pragma unroll
    for (int j = 0; j < 4; ++j) { hi[j] = f2bf(vv[j]); lo[j] = f2bf(vv[j] - bf2f(hi[j])); }
    s16x4 h4 = {hi[0], hi[1], hi[2], hi[3]};
    s16x4 l4 = {lo[0], lo[1], lo[2], lo[3]};
    *reinterpret_cast<s16x4*>(X2 + (size_t)m * 2048 + k) = h4;
    *reinterpret_cast<s16x4*>(X2 + (size_t)m * 2048 + 1024 + k) = l4;
}

// ---- Wq/Wk/Wv [1024][1024] f32 -> WT2 [3072][2048] bf16 (transposed; [n][k]: hi at k, lo at 1024+k)
__global__ void wqkv_conv(const float* __restrict__ Wq, const float* __restrict__ Wk,
                          const float* __restrict__ Wv, short* __restrict__ WT2) {
    __shared__ float t[32][33];
    int z = blockIdx.z;
    const float* W = (z == 0) ? Wq : (z == 1 ? Wk : Wv);
    int k0 = blockIdx.x * 32, n0 = blockIdx.y * 32;
    int tx = threadIdx.x, ty = threadIdx.y;
#pragma unroll
    for (int i = 0; i < 4; ++i)
        t[ty + 8 * i][tx] = W[(size_t)(k0 + ty + 8 * i) * 1024 + n0 + tx];
    __syncthreads();
#pragma unroll
    for (int i = 0; i < 4; ++i) {
        float v = t[tx][ty + 8 * i];
        short hi = f2bf(v), lo = f2bf(v - bf2f(hi));
        size_t r = (size_t)(z * 1024 + n0 + ty + 8 * i) * 2048 + k0 + tx;
        WT2[r] = hi;
        WT2[r + 1024] = lo;
    }
}

// ---- Wo [1024][1024] f32 -> WoT [1024][1024] bf16 (transposed, hi only)
__global__ void wo_conv(const float* __restrict__ Wo, short* __restrict__ WoT) {
    __shared__ float t[32][33];
    int k0 = blockIdx.x * 32, n0 = blockIdx.y * 32;
    int tx = threadIdx.x, ty = threadIdx.y;
#pragma unroll
    for (int i = 0; i < 4; ++i)
        t[ty + 8 * i][tx] = Wo[(size_t)(k0 + ty + 8 * i) * 1024 + n0 + tx];
    __syncthreads();
#pragma unroll
    for (int i = 0; i < 4; ++i)
        WoT[(size_t)(n0 + ty + 8 * i) * 1024 + k0 + tx] = f2bf(t[tx][ty + 8 * i]);
}

// ---- bias table [16][4096] bf16, PRE-SCALED by log2(e): tab[h][delta+2047] = log2e*rel_bias[bucket][h]
// Exact integer thresholds equivalent to int(log(rel/8)/log(16)*8) under correctly-rounded log.
__global__ void bias_kernel(const float* __restrict__ rel_bias, short* __restrict__ tab) {
    int idx = blockIdx.x * 256 + threadIdx.x;  // 16*4096
    int h = idx >> 12;
    int i = idx & 4095;
    int delta = i - 2047;
    int ad = delta < 0 ? -delta : delta;
    int b;
    if (ad < 8) b = ad;
    else if (ad < 12) b = 8;
    else if (ad < 16) b = 9;
    else if (ad < 23) b = 10;
    else if (ad < 32) b = 11;
    else if (ad < 46) b = 12;
    else if (ad < 64) b = 13;
    else if (ad < 91) b = 14;
    else b = 15;
    if (delta > 0) b += 16;
    tab[idx] = f2bf(rel_bias[b * 16 + h] * LOG2E);
}

// ---- GEMM (proven r5 m97-structure): C[M,N] = A[M,K'] * B[K',N], B given as B^T [N][K'].
// global_load_lds staging, single LDS buffer, 2 barriers per K-step.
// Split-K' remap: colA = kk - (kk>=aWrap ? aWrap : 0), same for B.
// EPI=0: fp32 C.
// EPI=1 (fused QKV, r12): region = n0>>10 (block-uniform).
//   Q region: nkUse=64 (XhWh + XhWl; drops XlWh per error budget), writes hi|lo 128-wide.
//   K region: nkUse=64 (same 2-term), writes hi ONLY to 64-wide k2 (flash drops Kl term).
//   V region: nkUse=32 (XhWh only), writes V^T bf16.
template <int EPI>
__launch_bounds__(256)
__global__ void gemm_bt(const short* __restrict__ A, const short* __restrict__ Bt,
                        int K, int lda, int ldb, int aWrap, int bWrap,
                        float* __restrict__ C, int ldc,
                        short* __restrict__ q2, short* __restrict__ k2, short* __restrict__ vt) {
    __shared__ __align__(16) short As[128 * 32];
    __shared__ __align__(16) short Bs[128 * 32];
    const int tid = threadIdx.x;
    const int w = tid >> 6, l = tid & 63;
    const int m0 = blockIdx.x * 128, n0 = blockIdx.y * 128;
    const int wm = (w >> 1) * 64, wn = (w & 1) * 64;
    const int ar = tid >> 2, ac = (tid & 3) * 8;
    const int wb = w * 512;

    const int region = (EPI == 1) ? (n0 >> 10) : 0;  // 0=Q 1=K 2=V (block-uniform)

    f32x4 acc[4][4];
#pragma unroll
    for (int i = 0; i < 4; ++i)
#pragma unroll
        for (int j = 0; j < 4; ++j) acc[i][j] = (f32x4){0.f, 0.f, 0.f, 0.f};

    const int nk = K / 32;
    const int nkUse = (EPI == 1) ? (region == 2 ? 32 : 64) : nk;
    for (int kt = 0; kt < nkUse; ++kt) {
        int kk = kt * 32;
        int ca = kk - (kk >= aWrap ? aWrap : 0);
        int cb = kk - (kk >= bWrap ? bWrap : 0);
        cp16(A + (size_t)(m0 + ar) * lda + ca + ac, As + wb);
        cp16(A + (size_t)(m0 + 64 + ar) * lda + ca + ac, As + 2048 + wb);
        cp16(Bt + (size_t)(n0 + ar) * ldb + cb + ac, Bs + wb);
        cp16(Bt + (size_t)(n0 + 64 + ar) * ldb + cb + ac, Bs + 2048 + wb);
        __syncthreads();
        s16x8 af[4], bfv[4];
#pragma unroll
        for (int i = 0; i < 4; ++i)
            af[i] = *reinterpret_cast<const s16x8*>(As + (wm + i * 16 + (l & 15)) * 32 + (l >> 4) * 8);
#pragma unroll
        for (int i = 0; i < 4; ++i)
            bfv[i] = *reinterpret_cast<const s16x8*>(Bs + (wn + i * 16 + (l & 15)) * 32 + (l >> 4) * 8);
#pragma unroll
        for (int mi = 0; mi < 4; ++mi)
#pragma unroll
            for (int ni = 0; ni < 4; ++ni)
                acc[mi][ni] = __builtin_amdgcn_mfma_f32_16x16x32_bf16(af[mi], bfv[ni], acc[mi][ni], 0, 0, 0);
        __syncthreads();
    }

    const int rl = l >> 4, cl = l & 15;
    if (EPI == 0) {
#pragma unroll
        for (int mi = 0; mi < 4; ++mi) {
            int row = m0 + wm + mi * 16 + rl * 4;
#pragma unroll
            for (int ni = 0; ni < 4; ++ni) {
                int col = n0 + wn + ni * 16 + cl;
#pragma unroll
                for (int r = 0; r < 4; ++r)
                    C[(size_t)(row + r) * ldc + col] = acc[mi][ni][r];
            }
        }
    } else {
#pragma unroll
        for (int mi = 0; mi < 4; ++mi) {
#pragma unroll
            for (int ni = 0; ni < 4; ++ni) {
#pragma unroll
                for (int r = 0; r < 4; ++r) {
                    int m = m0 + wm + mi * 16 + rl * 4 + r;
                    int n = (n0 & 1023) + wn + ni * 16 + cl;
                    int bb = m >> 11, s = m & 2047;
                    int h = n >> 6, d = n & 63;
                    int bh = bb * 16 + h;
                    float c = acc[mi][ni][r];
                    if (region == 0) {
                        c *= LOG2E;  // fold softmax base-2 conversion into Q
                        short hi = f2bf(c);
                        short lo = f2bf(c - bf2f(hi));
                        size_t base = ((size_t)bh * 2048 + s) * 128;
                        q2[base + d] = hi;
                        q2[base + 64 + d] = lo;
                    } else if (region == 1) {
                        // K: hi only (flash drops the Kl term), 64-wide layout
                        k2[((size_t)bh * 2048 + s) * 64 + d] = f2bf(c);
                    } else {
                        vt[((size_t)bh * 64 + d) * 2048 + s] = f2bf(c);
                    }
                }
            }
        }
    }
}

// ---- Flash attention, 32x32 swapped-operand form (validated r5/r8/r10).
// Grid: 512 blocks (XCD-swizzled), 512 threads = 8 waves; wave owns 32 q-rows (q-block 256).
// Swapped QK: mfma(A=Kh, B=Q') -> lane holds 16 scores of ONE q-row (q = lane&31).
// r12: K is hi-only (64-wide) -> 8 QK MFMAs (Kh.Qh + Kh.Ql), K LDS tile halves.
// P stays in registers; cross-half exchange via v_permlane32_swap_b32 (VALU).
// Bias pairs read as ONE aligned ds_read_b32 via dual-parity tables Bsh0/Bsh1.
// Index bound: i0 = kvg - qL + 255 <= 2301; Bsh0 fill 2304, Bsh1 fill 2302.
// No online max (|score*log2e| < ~90 << 127, exp2/fp32-sum safe); psum is in-lane scalar.
__launch_bounds__(512, 4)
__global__ void flash_kernel(const short* __restrict__ q2, const short* __restrict__ k2,
                             const short* __restrict__ vt, const short* __restrict__ btab,
                             short* __restrict__ attnb) {
    __shared__ __align__(16) short Ks[2][4096];   // [buf] 64 rows x 8 chunks(16B), slot = c ^ (r&7)
    __shared__ __align__(16) short Vs[2][4096];   // [buf] 64 d-rows x 8 chunks, slot = c ^ (d&7)
    __shared__ __align__(16) short Bsh0[2304];    // bias slice (bf16, log2e-scaled)
    __shared__ __align__(16) short Bsh1[2304];    // same shifted by +1 (odd-parity pair reads)

    const int tid = threadIdx.x;
    const int w = tid >> 6, l = tid & 63;
    const int l31 = l & 31, hi = l >> 5;

    const int L = blockIdx.x;
    const int xcd = L & 7, idx = L >> 3;
    const int bh = xcd + 8 * (idx & 7);
    const int qb = idx >> 3;
    const int h = bh & 15;
    const int q0b = qb * 256;
    const int qw0 = q0b + w * 32;
    const int qL = w * 32 + l31;

    const short* Q = q2 + (size_t)bh * Sc * 128;
    const short* Kp = k2 + (size_t)bh * Sc * 64;   // 64-wide hi-only
    const short* V = vt + (size_t)bh * 64 * Sc;

    {
        int base = h * 4096 + 1792 - q0b;
        for (int i = tid; i < 2304; i += 512) Bsh0[i] = btab[base + i];
        for (int i = tid; i < 2302; i += 512) Bsh1[i] = btab[base + i + 1];
    }

    auto stage = [&](int buf, int it2) {
        int kv0 = it2 * 64;
        {
            int o = w * 64 + l;                    // K chunk index 0..511
            int r = o >> 3, cs = o & 7;
            int cg = cs ^ (r & 7);                 // inverse swizzle on global source
            cp16(Kp + (size_t)(kv0 + r) * 64 + cg * 8, &Ks[buf][(w * 64) * 8]);
        }
        {
            int o = w * 64 + l;                    // V chunk index 0..511
            int d = o >> 3, cs = o & 7;
            int cg = cs ^ (d & 7);
            cp16(V + (size_t)d * 2048 + kv0 + cg * 8, &Vs[buf][(w * 64) * 8]);
        }
    };

    s16x8 qf[8];
#pragma unroll
    for (int c = 0; c < 8; ++c)
        qf[c] = *reinterpret_cast<const s16x8*>(Q + (size_t)(qw0 + l31) * 128 + c * 16 + hi * 8);

    f32x16 accO[2];
#pragma unroll
    for (int i = 0; i < 16; ++i) { accO[0][i] = 0.f; accO[1][i] = 0.f; }
    float psum = 0.f;

    stage(0, 0);
    __syncthreads();

    for (int it = 0; it < 32; ++it) {
        const int cur = it & 1;
        if (it + 1 < 32) stage(cur ^ 1, it + 1);
        const int kv0 = it * 64;
#pragma unroll
        for (int T = 0; T < 2; ++T) {
            const int rA = T * 32 + l31;
            const int rsw = rA & 7;
            const short* kbase = &Ks[cur][rA * 64];
            s16x8 kh[4];
#pragma unroll
            for (int c = 0; c < 4; ++c)
                kh[c] = *reinterpret_cast<const s16x8*>(kbase + ((c * 2 + hi) ^ rsw) * 8);
            f32x16 acc = {0.f,0.f,0.f,0.f,0.f,0.f,0.f,0.f,0.f,0.f,0.f,0.f,0.f,0.f,0.f,0.f};
#pragma unroll
            for (int c = 0; c < 4; ++c)  // Kh . Qh
                acc = __builtin_amdgcn_mfma_f32_32x32x16_bf16(kh[c], qf[c], acc, 0, 0, 0);
#pragma unroll
            for (int c = 0; c < 4; ++c)  // Kh . Ql
                acc = __builtin_amdgcn_mfma_f32_32x32x16_bf16(kh[c], qf[c + 4], acc, 0, 0, 0);
#pragma unroll
            for (int t2 = 0; t2 < 2; ++t2) {
                u32 pk[4];
#pragma unroll
                for (int i = 0; i < 4; ++i) {
                    const int ii = t2 * 4 + i;
                    const int pstart = ((ii & 1) * 2) + ((ii >> 1) * 8);
                    const int kvg = kv0 + T * 32 + pstart + 4 * hi;  // even
                    const int i0 = kvg - qL + 255;
                    const short* bp = (i0 & 1) ? (Bsh1 + (i0 - 1)) : (Bsh0 + i0);
                    const u32 pr2 = *reinterpret_cast<const u32*>(bp);  // 4B-aligned
                    const float b0 = bf2f((short)(pr2 & 0xffff));
                    const float b1 = bf2f((short)(pr2 >> 16));
                    const int r0 = t2 * 8 + i * 2;
                    const float e0 = fexp2(acc[r0] + b0);
                    const float e1 = fexp2(acc[r0 + 1] + b1);
                    psum += e0 + e1;
                    pk[i] = pack2(e0, e1);
                }
                pl32swap(pk[0], pk[2]);
                pl32swap(pk[1], pk[3]);
                u32x4 pv4 = {pk[0], pk[1], pk[2], pk[3]};
                s16x8 pfrag = __builtin_bit_cast(s16x8, pv4);
                const int tg = T * 2 + t2;
#pragma unroll
                for (int dt = 0; dt < 2; ++dt) {
                    const int d = dt * 32 + l31;
                    s16x8 vf = *reinterpret_cast<const s16x8*>(
                        &Vs[cur][d * 64 + ((tg * 2 + hi) ^ (d & 7)) * 8]);
                    accO[dt] = __builtin_amdgcn_mfma_f32_32x32x16_bf16(pfrag, vf, accO[dt], 0, 0, 0);
                }
            }
        }
        __syncthreads();
    }

    psum += __shfl_xor(psum, 32);

    const int bb = bh >> 4;
#pragma unroll
    for (int r = 0; r < 16; ++r) {
        const int qloc = (r & 3) + 8 * (r >> 2) + 4 * hi;
        const float inv = frcp(__shfl(psum, qloc));
        const size_t rowbase = ((size_t)(bb * 2048 + qw0 + qloc)) * 1024 + h * 64;
#pragma unroll
        for (int dt = 0; dt < 2; ++dt)
            attnb[rowbase + dt * 32 + l31] = f2bf(accO[dt][r] * inv);
    }
}

extern "C" void kernel_launch(void* const* d_in, const int* in_sizes, int n_in,
                              void* d_out, int out_size, void* d_ws, size_t ws_size,
                              hipStream_t stream) {
    const float* X = (const float*)d_in[0];
    const float* Wq = (const float*)d_in[1];
    const float* Wk = (const float*)d_in[2];
    const float* Wv = (const float*)d_in[3];
    const float* Wo = (const float*)d_in[4];
    const float* RB = (const float*)d_in[5];

    char* ws = (char*)d_ws;
    size_t off = 0;
    auto alloc = [&](size_t bytes) {
        void* p = ws + off;
        off += (bytes + 255) & ~(size_t)255;
        return p;
    };
    short* X2 = (short*)alloc((size_t)8192 * 2048 * 2);
    short* WT2 = (short*)alloc((size_t)3072 * 2048 * 2);
    short* q2 = (short*)alloc((size_t)64 * 2048 * 128 * 2);
    short* k2 = (short*)alloc((size_t)64 * 2048 * 64 * 2);   // hi-only, 64-wide
    short* vt = (short*)alloc((size_t)64 * 64 * 2048 * 2);
    short* attn = (short*)alloc((size_t)8192 * 1024 * 2);
    short* WoT = (short*)alloc((size_t)1024 * 1024 * 2);
    short* btab = (short*)alloc((size_t)16 * 4096 * 2);

    xconv_kernel<<<8192, 256, 0, stream>>>(X, X2);
    wqkv_conv<<<dim3(32, 32, 3), dim3(32, 8), 0, stream>>>(Wq, Wk, Wv, WT2);
    wo_conv<<<dim3(32, 32), dim3(32, 8), 0, stream>>>(Wo, WoT);
    bias_kernel<<<256, 256, 0, stream>>>(RB, btab);
    // Fused QKV projection, one dispatch (1536 blocks): Q/K regions 2-term (exit kt=64),
    // V region 1-term (exit kt=32). A=[Xhi|Xhi|Xlo] via aWrap, B=[Whi|Wlo|Whi] via bWrap.
    gemm_bt<1><<<dim3(64, 24), 256, 0, stream>>>(X2, WT2, 3072, 2048, 2048, 1024, 2048,
                                                 nullptr, 0, q2, k2, vt);
    flash_kernel<<<512, 512, 0, stream>>>(q2, k2, vt, btab, attn);
    // Output projection (single bf16)
    gemm_bt<0><<<dim3(64, 8), 256, 0, stream>>>(attn, WoT, 1024, 1024, 1024, 1 << 30, 1 << 30,
                                                (float*)d_out, 1024, nullptr, nullptr, nullptr);
}

// Round 13
// 290.785 us; speedup vs baseline: 1.9917x; 1.0467x over previous
//
#include <hip/hip_runtime.h>
#include <hip/hip_bf16.h>
#include <cstdint>

#define DI __device__ __forceinline__

typedef __attribute__((ext_vector_type(4))) float f32x4;
typedef __attribute__((ext_vector_type(16))) float f32x16;
typedef __attribute__((ext_vector_type(8))) short s16x8;
typedef __attribute__((ext_vector_type(4))) short s16x4;
typedef __attribute__((ext_vector_type(4))) unsigned int u32x4;
typedef unsigned int u32;

constexpr int Sc = 2048;
constexpr float LOG2E = 1.44269504088896340736f;
// B=4, D=1024, H=16, DK=64, M = B*S = 8192, BH = 64

DI short f2bf(float x) {
    __hip_bfloat16 h = __float2bfloat16(x);
    return __builtin_bit_cast(short, h);
}
DI float bf2f(short x) {
    __hip_bfloat16 h = __builtin_bit_cast(__hip_bfloat16, x);
    return __bfloat162float(h);
}
// pack two f32 -> dword of 2 bf16 (lo = a, hi = b) via verified scalar converts
DI u32 pack2(float a, float b) {
    return (u32)(unsigned short)f2bf(a) | ((u32)(unsigned short)f2bf(b) << 16);
}
// swap rows: a' = [a.row0, b.row0]; b' = [a.row1, b.row1]  (rows = 32-lane halves)
DI void pl32swap(u32& a, u32& b) {
    asm("v_permlane32_swap_b32 %0, %1" : "+v"(a), "+v"(b));
}

// async 16B global -> LDS (dest = wave-uniform base + lane*16)
DI void cp16(const short* g, short* l) {
    __builtin_amdgcn_global_load_lds(
        (const __attribute__((address_space(1))) u32*)g,
        (__attribute__((address_space(3))) u32*)l, 16, 0, 0);
}

DI float fexp2(float x) {
#if __has_builtin(__builtin_amdgcn_exp2f)
    return __builtin_amdgcn_exp2f(x);
#else
    return exp2f(x);
#endif
}
DI float frcp(float x) {
#if __has_builtin(__builtin_amdgcn_rcpf)
    return __builtin_amdgcn_rcpf(x);
#else
    return 1.0f / x;
#endif
}

// ---- X [8192][1024] f32 -> X2h [8192][1024] bf16 (hi only; Xlo no longer read anywhere)
__global__ void xconv_kernel(const float* __restrict__ X, short* __restrict__ X2) {
    size_t i = ((size_t)blockIdx.x * 256 + threadIdx.x) * 4;
    float4 v = *reinterpret_cast<const float4*>(X + i);
    s16x4 h4 = {f2bf(v.x), f2bf(v.y), f2bf(v.z), f2bf(v.w)};
    *reinterpret_cast<s16x4*>(X2 + i) = h4;
}

// ---- Wq/Wk/Wv [1024][1024] f32 -> WT2 [3072][2048] bf16 (transposed; [n][k]: hi at k, lo at 1024+k)
__global__ void wqkv_conv(const float* __restrict__ Wq, const float* __restrict__ Wk,
                          const float* __restrict__ Wv, short* __restrict__ WT2) {
    __shared__ float t[32][33];
    int z = blockIdx.z;
    const float* W = (z == 0) ? Wq : (z == 1 ? Wk : Wv);
    int k0 = blockIdx.x * 32, n0 = blockIdx.y * 32;
    int tx = threadIdx.x, ty = threadIdx.y;
#pragma unroll
    for (int i = 0; i < 4; ++i)
        t[ty + 8 * i][tx] = W[(size_t)(k0 + ty + 8 * i) * 1024 + n0 + tx];
    __syncthreads();
#pragma unroll
    for (int i = 0; i < 4; ++i) {
        float v = t[tx][ty + 8 * i];
        short hi = f2bf(v), lo = f2bf(v - bf2f(hi));
        size_t r = (size_t)(z * 1024 + n0 + ty + 8 * i) * 2048 + k0 + tx;
        WT2[r] = hi;
        WT2[r + 1024] = lo;
    }
}

// ---- Wo [1024][1024] f32 -> WoT [1024][1024] bf16 (transposed, hi only)
__global__ void wo_conv(const float* __restrict__ Wo, short* __restrict__ WoT) {
    __shared__ float t[32][33];
    int k0 = blockIdx.x * 32, n0 = blockIdx.y * 32;
    int tx = threadIdx.x, ty = threadIdx.y;
#pragma unroll
    for (int i = 0; i < 4; ++i)
        t[ty + 8 * i][tx] = Wo[(size_t)(k0 + ty + 8 * i) * 1024 + n0 + tx];
    __syncthreads();
#pragma unroll
    for (int i = 0; i < 4; ++i)
        WoT[(size_t)(n0 + ty + 8 * i) * 1024 + k0 + tx] = f2bf(t[tx][ty + 8 * i]);
}

// ---- bias table [16][4096] bf16, PRE-SCALED by log2(e): tab[h][delta+2047] = log2e*rel_bias[bucket][h]
// Exact integer thresholds equivalent to int(log(rel/8)/log(16)*8) under correctly-rounded log.
__global__ void bias_kernel(const float* __restrict__ rel_bias, short* __restrict__ tab) {
    int idx = blockIdx.x * 256 + threadIdx.x;  // 16*4096
    int h = idx >> 12;
    int i = idx & 4095;
    int delta = i - 2047;
    int ad = delta < 0 ? -delta : delta;
    int b;
    if (ad < 8) b = ad;
    else if (ad < 12) b = 8;
    else if (ad < 16) b = 9;
    else if (ad < 23) b = 10;
    else if (ad < 32) b = 11;
    else if (ad < 46) b = 12;
    else if (ad < 64) b = 13;
    else if (ad < 91) b = 14;
    else b = 15;
    if (delta > 0) b += 16;
    tab[idx] = f2bf(rel_bias[b * 16 + h] * LOG2E);
}

// ---- GEMM (m97 2-barrier structure, r13: BK=64 + XOR-swizzled LDS).
// C[M,N] = A[M,K'] * B[K',N], B given as B^T [N][K'].  BK=64 halves the per-iteration
// vmcnt(0)-drain count vs BK=32 (the measured dominant cost); chunk-XOR swizzle
// (slot = chunk ^ (row&7), static per lane) kills the 8/16-way bank conflict.
// Staging: pre-swizzled GLOBAL source + linear LDS dest (global_load_lds rule).
// Accumulation order over K unchanged -> output bit-identical to r12.
// Split-K' remap: col = kk - (kk>=wrap ? wrap : 0).
// EPI=0: fp32 C.
// EPI=1 (fused QKV): region = n0>>10. Q: 32 iters (XhWh+XhWl), hi|lo 128-wide out.
//   K: 32 iters, hi-only 64-wide out. V: 16 iters (XhWh), V^T bf16 out.
template <int EPI>
__launch_bounds__(256)
__global__ void gemm_bt(const short* __restrict__ A, const short* __restrict__ Bt,
                        int K, int lda, int ldb, int aWrap, int bWrap,
                        float* __restrict__ C, int ldc,
                        short* __restrict__ q2, short* __restrict__ k2, short* __restrict__ vt) {
    __shared__ __align__(16) short As[128 * 64];
    __shared__ __align__(16) short Bs[128 * 64];
    const int tid = threadIdx.x;
    const int w = tid >> 6, l = tid & 63;
    const int m0 = blockIdx.x * 128, n0 = blockIdx.y * 128;
    const int wm = (w >> 1) * 64, wn = (w & 1) * 64;
    const int rl = l >> 4, cl = l & 15;

    const int region = (EPI == 1) ? (n0 >> 10) : 0;  // 0=Q 1=K 2=V (block-uniform)

    f32x4 acc[4][4];
#pragma unroll
    for (int i = 0; i < 4; ++i)
#pragma unroll
        for (int j = 0; j < 4; ++j) acc[i][j] = (f32x4){0.f, 0.f, 0.f, 0.f};

    const int nk = K / 64;
    const int nkUse = (EPI == 1) ? (region == 2 ? 16 : 32) : nk;

    // staging decomposition: 1024 chunks (16B) per 128x64 tile; issue j covers chunks
    // j*256 + w*64 + l. row = o>>3, slot = o&7, global chunk = slot ^ (row&7).
    const int o0 = w * 64 + l;
    const int sr0 = o0 >> 3;                 // row contribution (per j: +32 rows)
    const int scg = (o0 & 7) ^ (sr0 & 7);    // pre-swizzled global chunk (static)

    // fragment reads: row = (wm|wn) + i*16 + cl (row&7 == cl&7), byte chunk = ks*4+rl,
    // swizzled slot = (ks*4+rl) ^ (cl&7) -- static per lane per ks.
    const int sw = cl & 7;

    for (int kt = 0; kt < nkUse; ++kt) {
        int kk = kt * 64;
        int ca = kk - (kk >= aWrap ? aWrap : 0);
        int cb = kk - (kk >= bWrap ? bWrap : 0);
#pragma unroll
        for (int j = 0; j < 4; ++j) {
            int r = j * 32 + sr0;
            cp16(A + (size_t)(m0 + r) * lda + ca + scg * 8, As + (j * 256 + w * 64) * 8);
            cp16(Bt + (size_t)(n0 + r) * ldb + cb + scg * 8, Bs + (j * 256 + w * 64) * 8);
        }
        __syncthreads();
#pragma unroll
        for (int ks = 0; ks < 2; ++ks) {
            const int slot = ((ks << 2) | rl) ^ sw;
            s16x8 af[4], bfv[4];
#pragma unroll
            for (int i = 0; i < 4; ++i)
                af[i] = *reinterpret_cast<const s16x8*>(As + (wm + i * 16 + cl) * 64 + slot * 8);
#pragma unroll
            for (int i = 0; i < 4; ++i)
                bfv[i] = *reinterpret_cast<const s16x8*>(Bs + (wn + i * 16 + cl) * 64 + slot * 8);
#pragma unroll
            for (int mi = 0; mi < 4; ++mi)
#pragma unroll
                for (int ni = 0; ni < 4; ++ni)
                    acc[mi][ni] = __builtin_amdgcn_mfma_f32_16x16x32_bf16(af[mi], bfv[ni], acc[mi][ni], 0, 0, 0);
        }
        __syncthreads();
    }

    if (EPI == 0) {
#pragma unroll
        for (int mi = 0; mi < 4; ++mi) {
            int row = m0 + wm + mi * 16 + rl * 4;
#pragma unroll
            for (int ni = 0; ni < 4; ++ni) {
                int col = n0 + wn + ni * 16 + cl;
#pragma unroll
                for (int r = 0; r < 4; ++r)
                    C[(size_t)(row + r) * ldc + col] = acc[mi][ni][r];
            }
        }
    } else {
#pragma unroll
        for (int mi = 0; mi < 4; ++mi) {
#pragma unroll
            for (int ni = 0; ni < 4; ++ni) {
#pragma unroll
                for (int r = 0; r < 4; ++r) {
                    int m = m0 + wm + mi * 16 + rl * 4 + r;
                    int n = (n0 & 1023) + wn + ni * 16 + cl;
                    int bb = m >> 11, s = m & 2047;
                    int h = n >> 6, d = n & 63;
                    int bh = bb * 16 + h;
                    float c = acc[mi][ni][r];
                    if (region == 0) {
                        c *= LOG2E;  // fold softmax base-2 conversion into Q
                        short hi = f2bf(c);
                        short lo = f2bf(c - bf2f(hi));
                        size_t base = ((size_t)bh * 2048 + s) * 128;
                        q2[base + d] = hi;
                        q2[base + 64 + d] = lo;
                    } else if (region == 1) {
                        // K: hi only (flash drops the Kl term), 64-wide layout
                        k2[((size_t)bh * 2048 + s) * 64 + d] = f2bf(c);
                    } else {
                        vt[((size_t)bh * 64 + d) * 2048 + s] = f2bf(c);
                    }
                }
            }
        }
    }
}

// ---- Flash attention, 32x32 swapped-operand form (validated r5/r8/r10/r12).
// Grid: 512 blocks (XCD-swizzled), 512 threads = 8 waves; wave owns 32 q-rows (q-block 256).
// Swapped QK: mfma(A=Kh, B=Q') -> lane holds 16 scores of ONE q-row (q = lane&31).
// K is hi-only (64-wide) -> 8 QK MFMAs (Kh.Qh + Kh.Ql), K LDS tile 8KB.
// P stays in registers; cross-half exchange via v_permlane32_swap_b32 (VALU).
// Bias pairs read as ONE aligned ds_read_b32 via dual-parity tables Bsh0/Bsh1.
// Index bound: i0 = kvg - qL + 255 <= 2301; Bsh0 fill 2304, Bsh1 fill 2302.
// No online max (|score*log2e| < ~90 << 127, exp2/fp32-sum safe); psum is in-lane scalar.
__launch_bounds__(512, 4)
__global__ void flash_kernel(const short* __restrict__ q2, const short* __restrict__ k2,
                             const short* __restrict__ vt, const short* __restrict__ btab,
                             short* __restrict__ attnb) {
    __shared__ __align__(16) short Ks[2][4096];   // [buf] 64 rows x 8 chunks(16B), slot = c ^ (r&7)
    __shared__ __align__(16) short Vs[2][4096];   // [buf] 64 d-rows x 8 chunks, slot = c ^ (d&7)
    __shared__ __align__(16) short Bsh0[2304];    // bias slice (bf16, log2e-scaled)
    __shared__ __align__(16) short Bsh1[2304];    // same shifted by +1 (odd-parity pair reads)

    const int tid = threadIdx.x;
    const int w = tid >> 6, l = tid & 63;
    const int l31 = l & 31, hi = l >> 5;

    const int L = blockIdx.x;
    const int xcd = L & 7, idx = L >> 3;
    const int bh = xcd + 8 * (idx & 7);
    const int qb = idx >> 3;
    const int h = bh & 15;
    const int q0b = qb * 256;
    const int qw0 = q0b + w * 32;
    const int qL = w * 32 + l31;

    const short* Q = q2 + (size_t)bh * Sc * 128;
    const short* Kp = k2 + (size_t)bh * Sc * 64;   // 64-wide hi-only
    const short* V = vt + (size_t)bh * 64 * Sc;

    {
        int base = h * 4096 + 1792 - q0b;
        for (int i = tid; i < 2304; i += 512) Bsh0[i] = btab[base + i];
        for (int i = tid; i < 2302; i += 512) Bsh1[i] = btab[base + i + 1];
    }

    auto stage = [&](int buf, int it2) {
        int kv0 = it2 * 64;
        {
            int o = w * 64 + l;                    // K chunk index 0..511
            int r = o >> 3, cs = o & 7;
            int cg = cs ^ (r & 7);                 // inverse swizzle on global source
            cp16(Kp + (size_t)(kv0 + r) * 64 + cg * 8, &Ks[buf][(w * 64) * 8]);
        }
        {
            int o = w * 64 + l;                    // V chunk index 0..511
            int d = o >> 3, cs = o & 7;
            int cg = cs ^ (d & 7);
            cp16(V + (size_t)d * 2048 + kv0 + cg * 8, &Vs[buf][(w * 64) * 8]);
        }
    };

    s16x8 qf[8];
#pragma unroll
    for (int c = 0; c < 8; ++c)
        qf[c] = *reinterpret_cast<const s16x8*>(Q + (size_t)(qw0 + l31) * 128 + c * 16 + hi * 8);

    f32x16 accO[2];
#pragma unroll
    for (int i = 0; i < 16; ++i) { accO[0][i] = 0.f; accO[1][i] = 0.f; }
    float psum = 0.f;

    stage(0, 0);
    __syncthreads();

    for (int it = 0; it < 32; ++it) {
        const int cur = it & 1;
        if (it + 1 < 32) stage(cur ^ 1, it + 1);
        const int kv0 = it * 64;
#pragma unroll
        for (int T = 0; T < 2; ++T) {
            const int rA = T * 32 + l31;
            const int rsw = rA & 7;
            const short* kbase = &Ks[cur][rA * 64];
            s16x8 kh[4];
#pragma unroll
            for (int c = 0; c < 4; ++c)
                kh[c] = *reinterpret_cast<const s16x8*>(kbase + ((c * 2 + hi) ^ rsw) * 8);
            f32x16 acc = {0.f,0.f,0.f,0.f,0.f,0.f,0.f,0.f,0.f,0.f,0.f,0.f,0.f,0.f,0.f,0.f};
#pragma unroll
            for (int c = 0; c < 4; ++c)  // Kh . Qh
                acc = __builtin_amdgcn_mfma_f32_32x32x16_bf16(kh[c], qf[c], acc, 0, 0, 0);
#pragma unroll
            for (int c = 0; c < 4; ++c)  // Kh . Ql
                acc = __builtin_amdgcn_mfma_f32_32x32x16_bf16(kh[c], qf[c + 4], acc, 0, 0, 0);
#pragma unroll
            for (int t2 = 0; t2 < 2; ++t2) {
                u32 pk[4];
#pragma unroll
                for (int i = 0; i < 4; ++i) {
                    const int ii = t2 * 4 + i;
                    const int pstart = ((ii & 1) * 2) + ((ii >> 1) * 8);
                    const int kvg = kv0 + T * 32 + pstart + 4 * hi;  // even
                    const int i0 = kvg - qL + 255;
                    const short* bp = (i0 & 1) ? (Bsh1 + (i0 - 1)) : (Bsh0 + i0);
                    const u32 pr2 = *reinterpret_cast<const u32*>(bp);  // 4B-aligned
                    const float b0 = bf2f((short)(pr2 & 0xffff));
                    const float b1 = bf2f((short)(pr2 >> 16));
                    const int r0 = t2 * 8 + i * 2;
                    const float e0 = fexp2(acc[r0] + b0);
                    const float e1 = fexp2(acc[r0 + 1] + b1);
                    psum += e0 + e1;
                    pk[i] = pack2(e0, e1);
                }
                pl32swap(pk[0], pk[2]);
                pl32swap(pk[1], pk[3]);
                u32x4 pv4 = {pk[0], pk[1], pk[2], pk[3]};
                s16x8 pfrag = __builtin_bit_cast(s16x8, pv4);
                const int tg = T * 2 + t2;
#pragma unroll
                for (int dt = 0; dt < 2; ++dt) {
                    const int d = dt * 32 + l31;
                    s16x8 vf = *reinterpret_cast<const s16x8*>(
                        &Vs[cur][d * 64 + ((tg * 2 + hi) ^ (d & 7)) * 8]);
                    accO[dt] = __builtin_amdgcn_mfma_f32_32x32x16_bf16(pfrag, vf, accO[dt], 0, 0, 0);
                }
            }
        }
        __syncthreads();
    }

    psum += __shfl_xor(psum, 32);

    const int bb = bh >> 4;
#pragma unroll
    for (int r = 0; r < 16; ++r) {
        const int qloc = (r & 3) + 8 * (r >> 2) + 4 * hi;
        const float inv = frcp(__shfl(psum, qloc));
        const size_t rowbase = ((size_t)(bb * 2048 + qw0 + qloc)) * 1024 + h * 64;
#pragma unroll
        for (int dt = 0; dt < 2; ++dt)
            attnb[rowbase + dt * 32 + l31] = f2bf(accO[dt][r] * inv);
    }
}

extern "C" void kernel_launch(void* const* d_in, const int* in_sizes, int n_in,
                              void* d_out, int out_size, void* d_ws, size_t ws_size,
                              hipStream_t stream) {
    const float* X = (const float*)d_in[0];
    const float* Wq = (const float*)d_in[1];
    const float* Wk = (const float*)d_in[2];
    const float* Wv = (const float*)d_in[3];
    const float* Wo = (const float*)d_in[4];
    const float* RB = (const float*)d_in[5];

    char* ws = (char*)d_ws;
    size_t off = 0;
    auto alloc = [&](size_t bytes) {
        void* p = ws + off;
        off += (bytes + 255) & ~(size_t)255;
        return p;
    };
    short* X2 = (short*)alloc((size_t)8192 * 1024 * 2);      // X hi only
    short* WT2 = (short*)alloc((size_t)3072 * 2048 * 2);
    short* q2 = (short*)alloc((size_t)64 * 2048 * 128 * 2);
    short* k2 = (short*)alloc((size_t)64 * 2048 * 64 * 2);   // hi-only, 64-wide
    short* vt = (short*)alloc((size_t)64 * 64 * 2048 * 2);
    short* attn = (short*)alloc((size_t)8192 * 1024 * 2);
    short* WoT = (short*)alloc((size_t)1024 * 1024 * 2);
    short* btab = (short*)alloc((size_t)16 * 4096 * 2);

    xconv_kernel<<<8192, 256, 0, stream>>>(X, X2);
    wqkv_conv<<<dim3(32, 32, 3), dim3(32, 8), 0, stream>>>(Wq, Wk, Wv, WT2);
    wo_conv<<<dim3(32, 32), dim3(32, 8), 0, stream>>>(Wo, WoT);
    bias_kernel<<<256, 256, 0, stream>>>(RB, btab);
    // Fused QKV projection, one dispatch (1536 blocks), BK=64: Q/K 32 iters (2-term via
    // aWrap/bWrap remap), V 16 iters (XhWh). A = X2h (lda=1024), B = WT2 (ldb=2048).
    gemm_bt<1><<<dim3(64, 24), 256, 0, stream>>>(X2, WT2, 3072, 1024, 2048, 1024, 2048,
                                                 nullptr, 0, q2, k2, vt);
    flash_kernel<<<512, 512, 0, stream>>>(q2, k2, vt, btab, attn);
    // Output projection (single bf16), K=1024 -> 16 iters
    gemm_bt<0><<<dim3(64, 8), 256, 0, stream>>>(attn, WoT, 1024, 1024, 1024, 1 << 30, 1 << 30,
                                                (float*)d_out, 1024, nullptr, nullptr, nullptr);
}

// Round 14
// 269.351 us; speedup vs baseline: 2.1502x; 1.0796x over previous
//
#include <hip/hip_runtime.h>
#include <hip/hip_bf16.h>
#include <cstdint>

#define DI __device__ __forceinline__

typedef __attribute__((ext_vector_type(4))) float f32x4;
typedef __attribute__((ext_vector_type(16))) float f32x16;
typedef __attribute__((ext_vector_type(8))) short s16x8;
typedef __attribute__((ext_vector_type(4))) short s16x4;
typedef __attribute__((ext_vector_type(4))) unsigned int u32x4;
typedef unsigned int u32;

constexpr int Sc = 2048;
constexpr float LOG2E = 1.44269504088896340736f;
// B=4, D=1024, H=16, DK=64, M = B*S = 8192, BH = 64

DI short f2bf(float x) {
    __hip_bfloat16 h = __float2bfloat16(x);
    return __builtin_bit_cast(short, h);
}
DI float bf2f(short x) {
    __hip_bfloat16 h = __builtin_bit_cast(__hip_bfloat16, x);
    return __bfloat162float(h);
}
// pack two f32 -> dword of 2 bf16 (lo = a, hi = b) via verified scalar converts
DI u32 pack2(float a, float b) {
    return (u32)(unsigned short)f2bf(a) | ((u32)(unsigned short)f2bf(b) << 16);
}
// swap rows: a' = [a.row0, b.row0]; b' = [a.row1, b.row1]  (rows = 32-lane halves)
DI void pl32swap(u32& a, u32& b) {
    asm("v_permlane32_swap_b32 %0, %1" : "+v"(a), "+v"(b));
}

// async 16B global -> LDS (dest = wave-uniform base + lane*16)
DI void cp16(const short* g, short* l) {
    __builtin_amdgcn_global_load_lds(
        (const __attribute__((address_space(1))) u32*)g,
        (__attribute__((address_space(3))) u32*)l, 16, 0, 0);
}

DI float fexp2(float x) {
#if __has_builtin(__builtin_amdgcn_exp2f)
    return __builtin_amdgcn_exp2f(x);
#else
    return exp2f(x);
#endif
}
DI float frcp(float x) {
#if __has_builtin(__builtin_amdgcn_rcpf)
    return __builtin_amdgcn_rcpf(x);
#else
    return 1.0f / x;
#endif
}

// ---- X [8192][1024] f32 -> X2h [8192][1024] bf16 (hi only)
__global__ void xconv_kernel(const float* __restrict__ X, short* __restrict__ X2) {
    size_t i = ((size_t)blockIdx.x * 256 + threadIdx.x) * 4;
    float4 v = *reinterpret_cast<const float4*>(X + i);
    s16x4 h4 = {f2bf(v.x), f2bf(v.y), f2bf(v.z), f2bf(v.w)};
    *reinterpret_cast<s16x4*>(X2 + i) = h4;
}

// ---- Wq/Wk/Wv [1024][1024] f32 -> WT2 [3072][2048] bf16 (transposed; hi at k, lo at 1024+k)
//      z=3: Wo -> WoT [1024][1024] bf16 (transposed, hi only)  [merged wo_conv]
__global__ void wconv(const float* __restrict__ Wq, const float* __restrict__ Wk,
                      const float* __restrict__ Wv, const float* __restrict__ Wo,
                      short* __restrict__ WT2, short* __restrict__ WoT) {
    __shared__ float t[32][33];
    int z = blockIdx.z;
    const float* W = (z == 0) ? Wq : (z == 1 ? Wk : (z == 2 ? Wv : Wo));
    int k0 = blockIdx.x * 32, n0 = blockIdx.y * 32;
    int tx = threadIdx.x, ty = threadIdx.y;
#pragma unroll
    for (int i = 0; i < 4; ++i)
        t[ty + 8 * i][tx] = W[(size_t)(k0 + ty + 8 * i) * 1024 + n0 + tx];
    __syncthreads();
    if (z < 3) {
#pragma unroll
        for (int i = 0; i < 4; ++i) {
            float v = t[tx][ty + 8 * i];
            short hi = f2bf(v), lo = f2bf(v - bf2f(hi));
            size_t r = (size_t)(z * 1024 + n0 + ty + 8 * i) * 2048 + k0 + tx;
            WT2[r] = hi;
            WT2[r + 1024] = lo;
        }
    } else {
#pragma unroll
        for (int i = 0; i < 4; ++i)
            WoT[(size_t)(n0 + ty + 8 * i) * 1024 + k0 + tx] = f2bf(t[tx][ty + 8 * i]);
    }
}

// ---- bias table [16][4096] bf16, PRE-SCALED by log2(e): tab[h][delta+2047] = log2e*rel_bias[bucket][h]
// Exact integer thresholds equivalent to int(log(rel/8)/log(16)*8) under correctly-rounded log.
__global__ void bias_kernel(const float* __restrict__ rel_bias, short* __restrict__ tab) {
    int idx = blockIdx.x * 256 + threadIdx.x;  // 16*4096
    int h = idx >> 12;
    int i = idx & 4095;
    int delta = i - 2047;
    int ad = delta < 0 ? -delta : delta;
    int b;
    if (ad < 8) b = ad;
    else if (ad < 12) b = 8;
    else if (ad < 16) b = 9;
    else if (ad < 23) b = 10;
    else if (ad < 32) b = 11;
    else if (ad < 46) b = 12;
    else if (ad < 64) b = 13;
    else if (ad < 91) b = 14;
    else b = 15;
    if (delta > 0) b += 16;
    tab[idx] = f2bf(rel_bias[b * 16 + h] * LOG2E);
}

// ---- GEMM (m97 2-barrier structure, BK=64 + XOR-swizzled LDS; validated r13).
// C[M,N] = A[M,K'] * B[K',N], B given as B^T [N][K'].
// Staging: pre-swizzled GLOBAL source + linear LDS dest; slot = chunk ^ (row&7).
// Split-K' remap: col = kk - (kk>=wrap ? wrap : 0).
// EPI=0: fp32 C.
// EPI=1 (fused QKV): region = n0>>10. Q: 32 iters (XhWh+XhWl), hi|lo 128-wide out.
//   K: 32 iters, hi-only 64-wide out. V: 16 iters (XhWh), V^T bf16 out.
template <int EPI>
__launch_bounds__(256)
__global__ void gemm_bt(const short* __restrict__ A, const short* __restrict__ Bt,
                        int K, int lda, int ldb, int aWrap, int bWrap,
                        float* __restrict__ C, int ldc,
                        short* __restrict__ q2, short* __restrict__ k2, short* __restrict__ vt) {
    __shared__ __align__(16) short As[128 * 64];
    __shared__ __align__(16) short Bs[128 * 64];
    const int tid = threadIdx.x;
    const int w = tid >> 6, l = tid & 63;
    const int m0 = blockIdx.x * 128, n0 = blockIdx.y * 128;
    const int wm = (w >> 1) * 64, wn = (w & 1) * 64;
    const int rl = l >> 4, cl = l & 15;

    const int region = (EPI == 1) ? (n0 >> 10) : 0;  // 0=Q 1=K 2=V (block-uniform)

    f32x4 acc[4][4];
#pragma unroll
    for (int i = 0; i < 4; ++i)
#pragma unroll
        for (int j = 0; j < 4; ++j) acc[i][j] = (f32x4){0.f, 0.f, 0.f, 0.f};

    const int nk = K / 64;
    const int nkUse = (EPI == 1) ? (region == 2 ? 16 : 32) : nk;

    const int o0 = w * 64 + l;
    const int sr0 = o0 >> 3;
    const int scg = (o0 & 7) ^ (sr0 & 7);
    const int sw = cl & 7;

    for (int kt = 0; kt < nkUse; ++kt) {
        int kk = kt * 64;
        int ca = kk - (kk >= aWrap ? aWrap : 0);
        int cb = kk - (kk >= bWrap ? bWrap : 0);
#pragma unroll
        for (int j = 0; j < 4; ++j) {
            int r = j * 32 + sr0;
            cp16(A + (size_t)(m0 + r) * lda + ca + scg * 8, As + (j * 256 + w * 64) * 8);
            cp16(Bt + (size_t)(n0 + r) * ldb + cb + scg * 8, Bs + (j * 256 + w * 64) * 8);
        }
        __syncthreads();
#pragma unroll
        for (int ks = 0; ks < 2; ++ks) {
            const int slot = ((ks << 2) | rl) ^ sw;
            s16x8 af[4], bfv[4];
#pragma unroll
            for (int i = 0; i < 4; ++i)
                af[i] = *reinterpret_cast<const s16x8*>(As + (wm + i * 16 + cl) * 64 + slot * 8);
#pragma unroll
            for (int i = 0; i < 4; ++i)
                bfv[i] = *reinterpret_cast<const s16x8*>(Bs + (wn + i * 16 + cl) * 64 + slot * 8);
#pragma unroll
            for (int mi = 0; mi < 4; ++mi)
#pragma unroll
                for (int ni = 0; ni < 4; ++ni)
                    acc[mi][ni] = __builtin_amdgcn_mfma_f32_16x16x32_bf16(af[mi], bfv[ni], acc[mi][ni], 0, 0, 0);
        }
        __syncthreads();
    }

    if (EPI == 0) {
#pragma unroll
        for (int mi = 0; mi < 4; ++mi) {
            int row = m0 + wm + mi * 16 + rl * 4;
#pragma unroll
            for (int ni = 0; ni < 4; ++ni) {
                int col = n0 + wn + ni * 16 + cl;
#pragma unroll
                for (int r = 0; r < 4; ++r)
                    C[(size_t)(row + r) * ldc + col] = acc[mi][ni][r];
            }
        }
    } else {
#pragma unroll
        for (int mi = 0; mi < 4; ++mi) {
#pragma unroll
            for (int ni = 0; ni < 4; ++ni) {
#pragma unroll
                for (int r = 0; r < 4; ++r) {
                    int m = m0 + wm + mi * 16 + rl * 4 + r;
                    int n = (n0 & 1023) + wn + ni * 16 + cl;
                    int bb = m >> 11, s = m & 2047;
                    int h = n >> 6, d = n & 63;
                    int bh = bb * 16 + h;
                    float c = acc[mi][ni][r];
                    if (region == 0) {
                        c *= LOG2E;  // fold softmax base-2 conversion into Q
                        short hi = f2bf(c);
                        short lo = f2bf(c - bf2f(hi));
                        size_t base = ((size_t)bh * 2048 + s) * 128;
                        q2[base + d] = hi;
                        q2[base + 64 + d] = lo;
                    } else if (region == 1) {
                        k2[((size_t)bh * 2048 + s) * 64 + d] = f2bf(c);
                    } else {
                        vt[((size_t)bh * 64 + d) * 2048 + s] = f2bf(c);
                    }
                }
            }
        }
    }
}

// ---- Flash attention, 32x32 swapped-operand form (validated r5/r8/r10/r12/r13).
// Grid: 512 blocks (XCD-swizzled), 512 threads = 8 waves; wave owns 32 q-rows (q-block 256).
// Swapped QK: mfma(A=Kh, B=Q') -> lane holds 16 scores of ONE q-row (q = lane&31).
// r14: FAR-TILE BIAS SHORTCUT -- the T5 bucket is constant for |delta|>=91 (bucket 15/31),
// and "whole 32-kv subtile far, single sign" is wave-uniform (qw range 32, kv range 32).
// ~87% of (wave, subtile) pairs skip all 8 bias LDS reads + parity addressing; bias value
// is the identical table entry -> output bit-identical.
// P stays in registers; cross-half exchange via v_permlane32_swap_b32 (VALU).
// Near tiles: bias pairs read as ONE aligned ds_read_b32 via dual-parity Bsh0/Bsh1.
// Index bound: i0 = kvg - qL + 255 <= 2301; Bsh0 fill 2304, Bsh1 fill 2302.
// No online max (|score*log2e| < ~90 << 127, exp2/fp32-sum safe); psum is in-lane scalar.
__launch_bounds__(512, 4)
__global__ void flash_kernel(const short* __restrict__ q2, const short* __restrict__ k2,
                             const short* __restrict__ vt, const short* __restrict__ btab,
                             short* __restrict__ attnb) {
    __shared__ __align__(16) short Ks[2][4096];   // [buf] 64 rows x 8 chunks(16B), slot = c ^ (r&7)
    __shared__ __align__(16) short Vs[2][4096];   // [buf] 64 d-rows x 8 chunks, slot = c ^ (d&7)
    __shared__ __align__(16) short Bsh0[2304];    // bias slice (bf16, log2e-scaled)
    __shared__ __align__(16) short Bsh1[2304];    // same shifted by +1 (odd-parity pair reads)

    const int tid = threadIdx.x;
    const int w = tid >> 6, l = tid & 63;
    const int l31 = l & 31, hi = l >> 5;

    const int L = blockIdx.x;
    const int xcd = L & 7, idx = L >> 3;
    const int bh = xcd + 8 * (idx & 7);
    const int qb = idx >> 3;
    const int h = bh & 15;
    const int q0b = qb * 256;
    const int qw0 = q0b + w * 32;     // global first q-row of this wave
    const int qL = w * 32 + l31;      // block-local q row

    const short* Q = q2 + (size_t)bh * Sc * 128;
    const short* Kp = k2 + (size_t)bh * Sc * 64;   // 64-wide hi-only
    const short* V = vt + (size_t)bh * 64 * Sc;

    // far-bias constants (exact table entries for |delta| >= 91)
    const float bneg = bf2f(btab[h * 4096 + 2047 - 91]);
    const float bpos = bf2f(btab[h * 4096 + 2047 + 91]);

    {
        int base = h * 4096 + 1792 - q0b;
        for (int i = tid; i < 2304; i += 512) Bsh0[i] = btab[base + i];
        for (int i = tid; i < 2302; i += 512) Bsh1[i] = btab[base + i + 1];
    }

    auto stage = [&](int buf, int it2) {
        int kv0 = it2 * 64;
        {
            int o = w * 64 + l;                    // K chunk index 0..511
            int r = o >> 3, cs = o & 7;
            int cg = cs ^ (r & 7);
            cp16(Kp + (size_t)(kv0 + r) * 64 + cg * 8, &Ks[buf][(w * 64) * 8]);
        }
        {
            int o = w * 64 + l;                    // V chunk index 0..511
            int d = o >> 3, cs = o & 7;
            int cg = cs ^ (d & 7);
            cp16(V + (size_t)d * 2048 + kv0 + cg * 8, &Vs[buf][(w * 64) * 8]);
        }
    };

    s16x8 qf[8];
#pragma unroll
    for (int c = 0; c < 8; ++c)
        qf[c] = *reinterpret_cast<const s16x8*>(Q + (size_t)(qw0 - q0b + q0b + l31) * 128 + c * 16 + hi * 8);
    // (qw0-q0b+q0b = qw0; kept simple below)
#pragma unroll
    for (int c = 0; c < 8; ++c)
        qf[c] = *reinterpret_cast<const s16x8*>(Q + (size_t)(qw0 + l31) * 128 + c * 16 + hi * 8);

    f32x16 accO[2];
#pragma unroll
    for (int i = 0; i < 16; ++i) { accO[0][i] = 0.f; accO[1][i] = 0.f; }
    float psum = 0.f;

    stage(0, 0);
    __syncthreads();

    for (int it = 0; it < 32; ++it) {
        const int cur = it & 1;
        if (it + 1 < 32) stage(cur ^ 1, it + 1);
        const int kv0 = it * 64;
#pragma unroll
        for (int T = 0; T < 2; ++T) {
            const int rA = T * 32 + l31;
            const int rsw = rA & 7;
            const short* kbase = &Ks[cur][rA * 64];
            s16x8 kh[4];
#pragma unroll
            for (int c = 0; c < 4; ++c)
                kh[c] = *reinterpret_cast<const s16x8*>(kbase + ((c * 2 + hi) ^ rsw) * 8);
            f32x16 acc = {0.f,0.f,0.f,0.f,0.f,0.f,0.f,0.f,0.f,0.f,0.f,0.f,0.f,0.f,0.f,0.f};
#pragma unroll
            for (int c = 0; c < 4; ++c)  // Kh . Qh
                acc = __builtin_amdgcn_mfma_f32_32x32x16_bf16(kh[c], qf[c], acc, 0, 0, 0);
#pragma unroll
            for (int c = 0; c < 4; ++c)  // Kh . Ql
                acc = __builtin_amdgcn_mfma_f32_32x32x16_bf16(kh[c], qf[c + 4], acc, 0, 0, 0);

            // wave-uniform far test for this 32-kv subtile vs this wave's 32 q-rows
            const int kvT0 = kv0 + T * 32;
            const int dmax = kvT0 + 31 - qw0;   // max delta over (lane, elem)
            const int dmin = kvT0 - qw0 - 31;   // min delta
            const bool faru = (dmax <= -91) || (dmin >= 91);
            const float bunif = (dmax <= -91) ? bneg : bpos;

            auto softpv = [&](bool far) {
#pragma unroll
                for (int t2 = 0; t2 < 2; ++t2) {
                    u32 pk[4];
#pragma unroll
                    for (int i = 0; i < 4; ++i) {
                        const int ii = t2 * 4 + i;
                        const int pstart = ((ii & 1) * 2) + ((ii >> 1) * 8);
                        float b0, b1;
                        if (far) {
                            b0 = bunif; b1 = bunif;
                        } else {
                            const int kvg = kv0 + T * 32 + pstart + 4 * hi;  // even
                            const int i0 = kvg - qL + 255;
                            const short* bp = (i0 & 1) ? (Bsh1 + (i0 - 1)) : (Bsh0 + i0);
                            const u32 pr2 = *reinterpret_cast<const u32*>(bp);  // 4B-aligned
                            b0 = bf2f((short)(pr2 & 0xffff));
                            b1 = bf2f((short)(pr2 >> 16));
                        }
                        const int r0 = t2 * 8 + i * 2;
                        const float e0 = fexp2(acc[r0] + b0);
                        const float e1 = fexp2(acc[r0 + 1] + b1);
                        psum += e0 + e1;
                        pk[i] = pack2(e0, e1);
                    }
                    pl32swap(pk[0], pk[2]);
                    pl32swap(pk[1], pk[3]);
                    u32x4 pv4 = {pk[0], pk[1], pk[2], pk[3]};
                    s16x8 pfrag = __builtin_bit_cast(s16x8, pv4);
                    const int tg = T * 2 + t2;
#pragma unroll
                    for (int dt = 0; dt < 2; ++dt) {
                        const int d = dt * 32 + l31;
                        s16x8 vf = *reinterpret_cast<const s16x8*>(
                            &Vs[cur][d * 64 + ((tg * 2 + hi) ^ (d & 7)) * 8]);
                        accO[dt] = __builtin_amdgcn_mfma_f32_32x32x16_bf16(pfrag, vf, accO[dt], 0, 0, 0);
                    }
                }
            };
            if (faru) softpv(true);   // wave-uniform branch: skips all bias LDS reads
            else      softpv(false);
        }
        __syncthreads();
    }

    psum += __shfl_xor(psum, 32);

    const int bb = bh >> 4;
#pragma unroll
    for (int r = 0; r < 16; ++r) {
        const int qloc = (r & 3) + 8 * (r >> 2) + 4 * hi;
        const float inv = frcp(__shfl(psum, qloc));
        const size_t rowbase = ((size_t)(bb * 2048 + qw0 + qloc)) * 1024 + h * 64;
#pragma unroll
        for (int dt = 0; dt < 2; ++dt)
            attnb[rowbase + dt * 32 + l31] = f2bf(accO[dt][r] * inv);
    }
}

extern "C" void kernel_launch(void* const* d_in, const int* in_sizes, int n_in,
                              void* d_out, int out_size, void* d_ws, size_t ws_size,
                              hipStream_t stream) {
    const float* X = (const float*)d_in[0];
    const float* Wq = (const float*)d_in[1];
    const float* Wk = (const float*)d_in[2];
    const float* Wv = (const float*)d_in[3];
    const float* Wo = (const float*)d_in[4];
    const float* RB = (const float*)d_in[5];

    char* ws = (char*)d_ws;
    size_t off = 0;
    auto alloc = [&](size_t bytes) {
        void* p = ws + off;
        off += (bytes + 255) & ~(size_t)255;
        return p;
    };
    short* X2 = (short*)alloc((size_t)8192 * 1024 * 2);      // X hi only
    short* WT2 = (short*)alloc((size_t)3072 * 2048 * 2);
    short* q2 = (short*)alloc((size_t)64 * 2048 * 128 * 2);
    short* k2 = (short*)alloc((size_t)64 * 2048 * 64 * 2);   // hi-only, 64-wide
    short* vt = (short*)alloc((size_t)64 * 64 * 2048 * 2);
    short* attn = (short*)alloc((size_t)8192 * 1024 * 2);
    short* WoT = (short*)alloc((size_t)1024 * 1024 * 2);
    short* btab = (short*)alloc((size_t)16 * 4096 * 2);

    xconv_kernel<<<8192, 256, 0, stream>>>(X, X2);
    wconv<<<dim3(32, 32, 4), dim3(32, 8), 0, stream>>>(Wq, Wk, Wv, Wo, WT2, WoT);
    bias_kernel<<<256, 256, 0, stream>>>(RB, btab);
    // Fused QKV projection, one dispatch (1536 blocks), BK=64: Q/K 32 iters (2-term via
    // aWrap/bWrap remap), V 16 iters (XhWh). A = X2h (lda=1024), B = WT2 (ldb=2048).
    gemm_bt<1><<<dim3(64, 24), 256, 0, stream>>>(X2, WT2, 3072, 1024, 2048, 1024, 2048,
                                                 nullptr, 0, q2, k2, vt);
    flash_kernel<<<512, 512, 0, stream>>>(q2, k2, vt, btab, attn);
    // Output projection (single bf16), K=1024 -> 16 iters
    gemm_bt<0><<<dim3(64, 8), 256, 0, stream>>>(attn, WoT, 1024, 1024, 1024, 1 << 30, 1 << 30,
                                                (float*)d_out, 1024, nullptr, nullptr, nullptr);
}

// Round 15
// 251.351 us; speedup vs baseline: 2.3042x; 1.0716x over previous
//
#include <hip/hip_runtime.h>
#include <hip/hip_bf16.h>
#include <cstdint>

#define DI __device__ __forceinline__

typedef __attribute__((ext_vector_type(4))) float f32x4;
typedef __attribute__((ext_vector_type(16))) float f32x16;
typedef __attribute__((ext_vector_type(8))) short s16x8;
typedef __attribute__((ext_vector_type(4))) short s16x4;
typedef __attribute__((ext_vector_type(4))) unsigned int u32x4;
typedef unsigned int u32;

constexpr int Sc = 2048;
constexpr float LOG2E = 1.44269504088896340736f;
// B=4, D=1024, H=16, DK=64, M = B*S = 8192, BH = 64

DI short f2bf(float x) {
    __hip_bfloat16 h = __float2bfloat16(x);
    return __builtin_bit_cast(short, h);
}
DI float bf2f(short x) {
    __hip_bfloat16 h = __builtin_bit_cast(__hip_bfloat16, x);
    return __bfloat162float(h);
}
// pack two f32 -> dword of 2 bf16 (lo = a, hi = b) via verified scalar converts
DI u32 pack2(float a, float b) {
    return (u32)(unsigned short)f2bf(a) | ((u32)(unsigned short)f2bf(b) << 16);
}
// swap rows: a' = [a.row0, b.row0]; b' = [a.row1, b.row1]  (rows = 32-lane halves)
DI void pl32swap(u32& a, u32& b) {
    asm("v_permlane32_swap_b32 %0, %1" : "+v"(a), "+v"(b));
}

// async 16B global -> LDS (dest = wave-uniform base + lane*16)
DI void cp16(const short* g, short* l) {
    __builtin_amdgcn_global_load_lds(
        (const __attribute__((address_space(1))) u32*)g,
        (__attribute__((address_space(3))) u32*)l, 16, 0, 0);
}

DI float fexp2(float x) {
#if __has_builtin(__builtin_amdgcn_exp2f)
    return __builtin_amdgcn_exp2f(x);
#else
    return exp2f(x);
#endif
}
DI float frcp(float x) {
#if __has_builtin(__builtin_amdgcn_rcpf)
    return __builtin_amdgcn_rcpf(x);
#else
    return 1.0f / x;
#endif
}

// ---- X [8192][1024] f32 -> X2h [8192][1024] bf16 (hi only)
__global__ void xconv_kernel(const float* __restrict__ X, short* __restrict__ X2) {
    size_t i = ((size_t)blockIdx.x * 256 + threadIdx.x) * 4;
    float4 v = *reinterpret_cast<const float4*>(X + i);
    s16x4 h4 = {f2bf(v.x), f2bf(v.y), f2bf(v.z), f2bf(v.w)};
    *reinterpret_cast<s16x4*>(X2 + i) = h4;
}

// ---- Wq/Wk/Wv [1024][1024] f32 -> WT2 [3072][2048] bf16 (transposed; hi at k, lo at 1024+k)
//      z=3: Wo -> WoT [1024][1024] bf16 (transposed, hi only)
__global__ void wconv(const float* __restrict__ Wq, const float* __restrict__ Wk,
                      const float* __restrict__ Wv, const float* __restrict__ Wo,
                      short* __restrict__ WT2, short* __restrict__ WoT) {
    __shared__ float t[32][33];
    int z = blockIdx.z;
    const float* W = (z == 0) ? Wq : (z == 1 ? Wk : (z == 2 ? Wv : Wo));
    int k0 = blockIdx.x * 32, n0 = blockIdx.y * 32;
    int tx = threadIdx.x, ty = threadIdx.y;
#pragma unroll
    for (int i = 0; i < 4; ++i)
        t[ty + 8 * i][tx] = W[(size_t)(k0 + ty + 8 * i) * 1024 + n0 + tx];
    __syncthreads();
    if (z < 3) {
#pragma unroll
        for (int i = 0; i < 4; ++i) {
            float v = t[tx][ty + 8 * i];
            short hi = f2bf(v), lo = f2bf(v - bf2f(hi));
            size_t r = (size_t)(z * 1024 + n0 + ty + 8 * i) * 2048 + k0 + tx;
            WT2[r] = hi;
            WT2[r + 1024] = lo;
        }
    } else {
#pragma unroll
        for (int i = 0; i < 4; ++i)
            WoT[(size_t)(n0 + ty + 8 * i) * 1024 + k0 + tx] = f2bf(t[tx][ty + 8 * i]);
    }
}

// ---- bias table [16][4096] bf16, PRE-SCALED by log2(e): tab[h][delta+2047] = log2e*rel_bias[bucket][h]
// Exact integer thresholds equivalent to int(log(rel/8)/log(16)*8) under correctly-rounded log.
__global__ void bias_kernel(const float* __restrict__ rel_bias, short* __restrict__ tab) {
    int idx = blockIdx.x * 256 + threadIdx.x;  // 16*4096
    int h = idx >> 12;
    int i = idx & 4095;
    int delta = i - 2047;
    int ad = delta < 0 ? -delta : delta;
    int b;
    if (ad < 8) b = ad;
    else if (ad < 12) b = 8;
    else if (ad < 16) b = 9;
    else if (ad < 23) b = 10;
    else if (ad < 32) b = 11;
    else if (ad < 46) b = 12;
    else if (ad < 64) b = 13;
    else if (ad < 91) b = 14;
    else b = 15;
    if (delta > 0) b += 16;
    tab[idx] = f2bf(rel_bias[b * 16 + h] * LOG2E);
}

// ---- GEMM (m97 2-barrier structure, BK=64 + XOR-swizzled LDS; validated r13/r14).
// C[M,N] = A[M,K'] * B[K',N], B given as B^T [N][K'].
// Staging: pre-swizzled GLOBAL source + linear LDS dest; slot = chunk ^ (row&7).
// Split-K' remap: col = kk - (kk>=wrap ? wrap : 0).
// EPI=0: fp32 C.
// EPI=1 (fused QKV, r15): region = n0>>10.
//   Q: 32 iters (XhWh + XhWl), hi|lo 128-wide out.
//   K: 16 iters (XhWh only -- r15 error-budget bite; W-lo correction dropped), hi-only 64-wide out.
//   V: 16 iters (XhWh), V^T bf16 out.
template <int EPI>
__launch_bounds__(256)
__global__ void gemm_bt(const short* __restrict__ A, const short* __restrict__ Bt,
                        int K, int lda, int ldb, int aWrap, int bWrap,
                        float* __restrict__ C, int ldc,
                        short* __restrict__ q2, short* __restrict__ k2, short* __restrict__ vt) {
    __shared__ __align__(16) short As[128 * 64];
    __shared__ __align__(16) short Bs[128 * 64];
    const int tid = threadIdx.x;
    const int w = tid >> 6, l = tid & 63;
    const int m0 = blockIdx.x * 128, n0 = blockIdx.y * 128;
    const int wm = (w >> 1) * 64, wn = (w & 1) * 64;
    const int rl = l >> 4, cl = l & 15;

    const int region = (EPI == 1) ? (n0 >> 10) : 0;  // 0=Q 1=K 2=V (block-uniform)

    f32x4 acc[4][4];
#pragma unroll
    for (int i = 0; i < 4; ++i)
#pragma unroll
        for (int j = 0; j < 4; ++j) acc[i][j] = (f32x4){0.f, 0.f, 0.f, 0.f};

    const int nk = K / 64;
    const int nkUse = (EPI == 1) ? (region == 0 ? 32 : 16) : nk;

    const int o0 = w * 64 + l;
    const int sr0 = o0 >> 3;
    const int scg = (o0 & 7) ^ (sr0 & 7);
    const int sw = cl & 7;

    for (int kt = 0; kt < nkUse; ++kt) {
        int kk = kt * 64;
        int ca = kk - (kk >= aWrap ? aWrap : 0);
        int cb = kk - (kk >= bWrap ? bWrap : 0);
#pragma unroll
        for (int j = 0; j < 4; ++j) {
            int r = j * 32 + sr0;
            cp16(A + (size_t)(m0 + r) * lda + ca + scg * 8, As + (j * 256 + w * 64) * 8);
            cp16(Bt + (size_t)(n0 + r) * ldb + cb + scg * 8, Bs + (j * 256 + w * 64) * 8);
        }
        __syncthreads();
#pragma unroll
        for (int ks = 0; ks < 2; ++ks) {
            const int slot = ((ks << 2) | rl) ^ sw;
            s16x8 af[4], bfv[4];
#pragma unroll
            for (int i = 0; i < 4; ++i)
                af[i] = *reinterpret_cast<const s16x8*>(As + (wm + i * 16 + cl) * 64 + slot * 8);
#pragma unroll
            for (int i = 0; i < 4; ++i)
                bfv[i] = *reinterpret_cast<const s16x8*>(Bs + (wn + i * 16 + cl) * 64 + slot * 8);
#pragma unroll
            for (int mi = 0; mi < 4; ++mi)
#pragma unroll
                for (int ni = 0; ni < 4; ++ni)
                    acc[mi][ni] = __builtin_amdgcn_mfma_f32_16x16x32_bf16(af[mi], bfv[ni], acc[mi][ni], 0, 0, 0);
        }
        __syncthreads();
    }

    if (EPI == 0) {
#pragma unroll
        for (int mi = 0; mi < 4; ++mi) {
            int row = m0 + wm + mi * 16 + rl * 4;
#pragma unroll
            for (int ni = 0; ni < 4; ++ni) {
                int col = n0 + wn + ni * 16 + cl;
#pragma unroll
                for (int r = 0; r < 4; ++r)
                    C[(size_t)(row + r) * ldc + col] = acc[mi][ni][r];
            }
        }
    } else {
#pragma unroll
        for (int mi = 0; mi < 4; ++mi) {
#pragma unroll
            for (int ni = 0; ni < 4; ++ni) {
#pragma unroll
                for (int r = 0; r < 4; ++r) {
                    int m = m0 + wm + mi * 16 + rl * 4 + r;
                    int n = (n0 & 1023) + wn + ni * 16 + cl;
                    int bb = m >> 11, s = m & 2047;
                    int h = n >> 6, d = n & 63;
                    int bh = bb * 16 + h;
                    float c = acc[mi][ni][r];
                    if (region == 0) {
                        c *= LOG2E;  // fold softmax base-2 conversion into Q
                        short hi = f2bf(c);
                        short lo = f2bf(c - bf2f(hi));
                        size_t base = ((size_t)bh * 2048 + s) * 128;
                        q2[base + d] = hi;
                        q2[base + 64 + d] = lo;
                    } else if (region == 1) {
                        k2[((size_t)bh * 2048 + s) * 64 + d] = f2bf(c);
                    } else {
                        vt[((size_t)bh * 64 + d) * 2048 + s] = f2bf(c);
                    }
                }
            }
        }
    }
}

// ---- Flash attention, 32x32 swapped-operand form (validated r5/r8/r10/r12/r13/r14).
// Grid: 512 blocks (XCD-swizzled), 512 threads = 8 waves; wave owns 32 q-rows (q-block 256).
// Swapped QK: mfma(A=Kh, B=Q') -> lane holds 16 scores of ONE q-row (q = lane&31).
// K hi-only (64-wide) -> 8 QK MFMAs (Kh.Qh + Kh.Ql).
// FAR-TILE BIAS SHORTCUT (r14): bucket constant for |delta|>=91; wave-uniform far test
// skips all bias LDS reads for ~87% of subtiles (bit-identical value).
// P stays in registers; cross-half exchange via v_permlane32_swap_b32 (VALU).
// Near tiles: bias pairs read as ONE aligned ds_read_b32 via dual-parity Bsh0/Bsh1.
// Index bound: i0 = kvg - qL + 255 <= 2301; Bsh0 fill 2304, Bsh1 fill 2302.
// No online max (|score*log2e| < ~90 << 127, exp2/fp32-sum safe); psum is in-lane scalar.
__launch_bounds__(512, 4)
__global__ void flash_kernel(const short* __restrict__ q2, const short* __restrict__ k2,
                             const short* __restrict__ vt, const short* __restrict__ btab,
                             short* __restrict__ attnb) {
    __shared__ __align__(16) short Ks[2][4096];   // [buf] 64 rows x 8 chunks(16B), slot = c ^ (r&7)
    __shared__ __align__(16) short Vs[2][4096];   // [buf] 64 d-rows x 8 chunks, slot = c ^ (d&7)
    __shared__ __align__(16) short Bsh0[2304];    // bias slice (bf16, log2e-scaled)
    __shared__ __align__(16) short Bsh1[2304];    // same shifted by +1 (odd-parity pair reads)

    const int tid = threadIdx.x;
    const int w = tid >> 6, l = tid & 63;
    const int l31 = l & 31, hi = l >> 5;

    const int L = blockIdx.x;
    const int xcd = L & 7, idx = L >> 3;
    const int bh = xcd + 8 * (idx & 7);
    const int qb = idx >> 3;
    const int h = bh & 15;
    const int q0b = qb * 256;
    const int qw0 = q0b + w * 32;     // global first q-row of this wave
    const int qL = w * 32 + l31;      // block-local q row

    const short* Q = q2 + (size_t)bh * Sc * 128;
    const short* Kp = k2 + (size_t)bh * Sc * 64;   // 64-wide hi-only
    const short* V = vt + (size_t)bh * 64 * Sc;

    // far-bias constants (exact table entries for |delta| >= 91)
    const float bneg = bf2f(btab[h * 4096 + 2047 - 91]);
    const float bpos = bf2f(btab[h * 4096 + 2047 + 91]);

    {
        int base = h * 4096 + 1792 - q0b;
        for (int i = tid; i < 2304; i += 512) Bsh0[i] = btab[base + i];
        for (int i = tid; i < 2302; i += 512) Bsh1[i] = btab[base + i + 1];
    }

    auto stage = [&](int buf, int it2) {
        int kv0 = it2 * 64;
        {
            int o = w * 64 + l;                    // K chunk index 0..511
            int r = o >> 3, cs = o & 7;
            int cg = cs ^ (r & 7);
            cp16(Kp + (size_t)(kv0 + r) * 64 + cg * 8, &Ks[buf][(w * 64) * 8]);
        }
        {
            int o = w * 64 + l;                    // V chunk index 0..511
            int d = o >> 3, cs = o & 7;
            int cg = cs ^ (d & 7);
            cp16(V + (size_t)d * 2048 + kv0 + cg * 8, &Vs[buf][(w * 64) * 8]);
        }
    };

    s16x8 qf[8];
#pragma unroll
    for (int c = 0; c < 8; ++c)
        qf[c] = *reinterpret_cast<const s16x8*>(Q + (size_t)(qw0 + l31) * 128 + c * 16 + hi * 8);

    f32x16 accO[2];
#pragma unroll
    for (int i = 0; i < 16; ++i) { accO[0][i] = 0.f; accO[1][i] = 0.f; }
    float psum = 0.f;

    stage(0, 0);
    __syncthreads();

    for (int it = 0; it < 32; ++it) {
        const int cur = it & 1;
        if (it + 1 < 32) stage(cur ^ 1, it + 1);
        const int kv0 = it * 64;
#pragma unroll
        for (int T = 0; T < 2; ++T) {
            const int rA = T * 32 + l31;
            const int rsw = rA & 7;
            const short* kbase = &Ks[cur][rA * 64];
            s16x8 kh[4];
#pragma unroll
            for (int c = 0; c < 4; ++c)
                kh[c] = *reinterpret_cast<const s16x8*>(kbase + ((c * 2 + hi) ^ rsw) * 8);
            f32x16 acc = {0.f,0.f,0.f,0.f,0.f,0.f,0.f,0.f,0.f,0.f,0.f,0.f,0.f,0.f,0.f,0.f};
#pragma unroll
            for (int c = 0; c < 4; ++c)  // Kh . Qh
                acc = __builtin_amdgcn_mfma_f32_32x32x16_bf16(kh[c], qf[c], acc, 0, 0, 0);
#pragma unroll
            for (int c = 0; c < 4; ++c)  // Kh . Ql
                acc = __builtin_amdgcn_mfma_f32_32x32x16_bf16(kh[c], qf[c + 4], acc, 0, 0, 0);

            // wave-uniform far test for this 32-kv subtile vs this wave's 32 q-rows
            const int kvT0 = kv0 + T * 32;
            const int dmax = kvT0 + 31 - qw0;   // max delta over (lane, elem)
            const int dmin = kvT0 - qw0 - 31;   // min delta
            const bool faru = (dmax <= -91) || (dmin >= 91);
            const float bunif = (dmax <= -91) ? bneg : bpos;

            auto softpv = [&](bool far) {
#pragma unroll
                for (int t2 = 0; t2 < 2; ++t2) {
                    u32 pk[4];
#pragma unroll
                    for (int i = 0; i < 4; ++i) {
                        const int ii = t2 * 4 + i;
                        const int pstart = ((ii & 1) * 2) + ((ii >> 1) * 8);
                        float b0, b1;
                        if (far) {
                            b0 = bunif; b1 = bunif;
                        } else {
                            const int kvg = kv0 + T * 32 + pstart + 4 * hi;  // even
                            const int i0 = kvg - qL + 255;
                            const short* bp = (i0 & 1) ? (Bsh1 + (i0 - 1)) : (Bsh0 + i0);
                            const u32 pr2 = *reinterpret_cast<const u32*>(bp);  // 4B-aligned
                            b0 = bf2f((short)(pr2 & 0xffff));
                            b1 = bf2f((short)(pr2 >> 16));
                        }
                        const int r0 = t2 * 8 + i * 2;
                        const float e0 = fexp2(acc[r0] + b0);
                        const float e1 = fexp2(acc[r0 + 1] + b1);
                        psum += e0 + e1;
                        pk[i] = pack2(e0, e1);
                    }
                    pl32swap(pk[0], pk[2]);
                    pl32swap(pk[1], pk[3]);
                    u32x4 pv4 = {pk[0], pk[1], pk[2], pk[3]};
                    s16x8 pfrag = __builtin_bit_cast(s16x8, pv4);
                    const int tg = T * 2 + t2;
#pragma unroll
                    for (int dt = 0; dt < 2; ++dt) {
                        const int d = dt * 32 + l31;
                        s16x8 vf = *reinterpret_cast<const s16x8*>(
                            &Vs[cur][d * 64 + ((tg * 2 + hi) ^ (d & 7)) * 8]);
                        accO[dt] = __builtin_amdgcn_mfma_f32_32x32x16_bf16(pfrag, vf, accO[dt], 0, 0, 0);
                    }
                }
            };
            if (faru) softpv(true);   // wave-uniform branch: skips all bias LDS reads
            else      softpv(false);
        }
        __syncthreads();
    }

    psum += __shfl_xor(psum, 32);

    const int bb = bh >> 4;
#pragma unroll
    for (int r = 0; r < 16; ++r) {
        const int qloc = (r & 3) + 8 * (r >> 2) + 4 * hi;
        const float inv = frcp(__shfl(psum, qloc));
        const size_t rowbase = ((size_t)(bb * 2048 + qw0 + qloc)) * 1024 + h * 64;
#pragma unroll
        for (int dt = 0; dt < 2; ++dt)
            attnb[rowbase + dt * 32 + l31] = f2bf(accO[dt][r] * inv);
    }
}

extern "C" void kernel_launch(void* const* d_in, const int* in_sizes, int n_in,
                              void* d_out, int out_size, void* d_ws, size_t ws_size,
                              hipStream_t stream) {
    const float* X = (const float*)d_in[0];
    const float* Wq = (const float*)d_in[1];
    const float* Wk = (const float*)d_in[2];
    const float* Wv = (const float*)d_in[3];
    const float* Wo = (const float*)d_in[4];
    const float* RB = (const float*)d_in[5];

    char* ws = (char*)d_ws;
    size_t off = 0;
    auto alloc = [&](size_t bytes) {
        void* p = ws + off;
        off += (bytes + 255) & ~(size_t)255;
        return p;
    };
    short* X2 = (short*)alloc((size_t)8192 * 1024 * 2);      // X hi only
    short* WT2 = (short*)alloc((size_t)3072 * 2048 * 2);
    short* q2 = (short*)alloc((size_t)64 * 2048 * 128 * 2);
    short* k2 = (short*)alloc((size_t)64 * 2048 * 64 * 2);   // hi-only, 64-wide
    short* vt = (short*)alloc((size_t)64 * 64 * 2048 * 2);
    short* attn = (short*)alloc((size_t)8192 * 1024 * 2);
    short* WoT = (short*)alloc((size_t)1024 * 1024 * 2);
    short* btab = (short*)alloc((size_t)16 * 4096 * 2);

    xconv_kernel<<<8192, 256, 0, stream>>>(X, X2);
    wconv<<<dim3(32, 32, 4), dim3(32, 8), 0, stream>>>(Wq, Wk, Wv, Wo, WT2, WoT);
    bias_kernel<<<256, 256, 0, stream>>>(RB, btab);
    // Fused QKV projection, one dispatch (1536 blocks), BK=64:
    // Q 32 iters (2-term via aWrap/bWrap remap), K 16 iters (1-term, r15), V 16 iters.
    gemm_bt<1><<<dim3(64, 24), 256, 0, stream>>>(X2, WT2, 3072, 1024, 2048, 1024, 2048,
                                                 nullptr, 0, q2, k2, vt);
    flash_kernel<<<512, 512, 0, stream>>>(q2, k2, vt, btab, attn);
    // Output projection (single bf16), K=1024 -> 16 iters
    gemm_bt<0><<<dim3(64, 8), 256, 0, stream>>>(attn, WoT, 1024, 1024, 1024, 1 << 30, 1 << 30,
                                                (float*)d_out, 1024, nullptr, nullptr, nullptr);
}